// Round 2
// baseline (1232.144 us; speedup 1.0000x reference)
//
#include <hip/hip_runtime.h>
#include <hip/hip_bf16.h>
#include <math.h>

#define B_   2
#define Q_   2048
#define M_   2048
#define H_   16
#define D_   64
#define HID_ 1024
#define KL_  4096
#define RT_  64      // q rows per attention block
#define WT_  128     // k cols per attention tile

typedef short short8 __attribute__((ext_vector_type(8)));
typedef float f32x4 __attribute__((ext_vector_type(4)));

// read input element i as float, md=1 -> fp32 buffer, md=0 -> bf16 buffer
__device__ __forceinline__ float ldin(const void* p, size_t i, int md) {
  return md ? ((const float*)p)[i] : __bfloat162float(((const __hip_bfloat16*)p)[i]);
}

// ---------------- dtype detector: writes 1 if inputs are fp32, else 0 ----------------
__global__ __launch_bounds__(256) void detect_kernel(const unsigned int* __restrict__ q,
                                                     int* __restrict__ flag) {
  __shared__ int cnt;
  if (threadIdx.x == 0) cnt = 0;
  __syncthreads();
  int ins = 0;
#pragma unroll
  for (int i = 0; i < 4; i++) {
    unsigned int u = q[threadIdx.x * 4 + i];
    int e0 = (int)((u >> 7) & 0xffu);
    int e1 = (int)((u >> 23) & 0xffu);
    // sane bf16 exponent for N(0,1) data: ~[102,140]; NaN/Inf = 255
    if (e0 == 0xff || e0 < 102 || e0 > 140) ins++;
    if (e1 == 0xff || e1 < 102 || e1 > 140) ins++;
  }
  atomicAdd(&cnt, ins);
  __syncthreads();
  if (threadIdx.x == 0) *flag = (cnt > 512) ? 1 : 0;
}

// ---------------- weight transpose: wt[n][k] = src[k][n], 1024x1024 ----------------
__global__ __launch_bounds__(256) void wt_kernel(const void* __restrict__ src,
                                                 __hip_bfloat16* __restrict__ wt,
                                                 const int* __restrict__ mode) {
  const int md = *mode;
  const int r0 = blockIdx.x * 64, c0 = blockIdx.y * 64;
  __shared__ __hip_bfloat16 t[64][65];
  const int tid = threadIdx.x;
  const int col = tid & 63, r4 = tid >> 6;
#pragma unroll
  for (int i = 0; i < 16; i++)
    t[r4 + i * 4][col] = __float2bfloat16(ldin(src, (size_t)(r0 + r4 + i * 4) * HID_ + c0 + col, md));
  __syncthreads();
#pragma unroll
  for (int i = 0; i < 16; i++)
    wt[(size_t)(c0 + r4 + i * 4) * HID_ + r0 + col] = t[col][r4 + i * 4];
}

// ---------------- V transpose: vpt[b][h][d][j] = vp[b*K+j][h*64+d] ----------------
__global__ __launch_bounds__(256) void vpt_kernel(const __hip_bfloat16* __restrict__ vp,
                                                  __hip_bfloat16* __restrict__ vpt) {
  const int jt = blockIdx.x * 64;
  const int bh = blockIdx.y;
  const int b = bh / H_, h = bh % H_;
  __shared__ __hip_bfloat16 t[64][65];
  const int tid = threadIdx.x;
  const int col = tid & 63, r4 = tid >> 6;
#pragma unroll
  for (int i = 0; i < 16; i++) {
    int j = r4 + i * 4;
    t[j][col] = vp[((size_t)b * KL_ + jt + j) * HID_ + h * D_ + col];
  }
  __syncthreads();
#pragma unroll
  for (int i = 0; i < 16; i++) {
    int d = r4 + i * 4;
    vpt[(((size_t)b * H_ + h) * D_ + d) * KL_ + jt + col] = t[col][d];
  }
}

// ---------------- LayerNorm over concat(memory, query) rows ----------------
__global__ __launch_bounds__(256) void ln_kv_kernel(
    const void* __restrict__ mem, const void* __restrict__ qry,
    const void* __restrict__ gamma, const void* __restrict__ beta,
    __hip_bfloat16* __restrict__ out, const int* __restrict__ mode) {
  const int md = *mode;
  const int row = blockIdx.x;  // 0..B*KL-1
  const int b = row / KL_, j = row % KL_;
  const void* src;
  size_t base;
  if (j < M_) { src = mem; base = ((size_t)b * M_ + j) * HID_; }
  else        { src = qry; base = ((size_t)b * Q_ + (j - M_)) * HID_; }
  const int tid = threadIdx.x;
  float x[4];
  float s = 0.f, ss = 0.f;
#pragma unroll
  for (int i = 0; i < 4; i++) {
    x[i] = ldin(src, base + i * 256 + tid, md);
    s += x[i]; ss += x[i] * x[i];
  }
#pragma unroll
  for (int o = 32; o > 0; o >>= 1) { s += __shfl_down(s, o); ss += __shfl_down(ss, o); }
  __shared__ float red[8];
  if ((tid & 63) == 0) { red[(tid >> 6) * 2] = s; red[(tid >> 6) * 2 + 1] = ss; }
  __syncthreads();
  float ts = 0.f, tss = 0.f;
#pragma unroll
  for (int i = 0; i < 4; i++) { ts += red[i * 2]; tss += red[i * 2 + 1]; }
  const float mu = ts * (1.f / 1024.f);
  const float var = tss * (1.f / 1024.f) - mu * mu;
  const float rs = rsqrtf(var + 1e-3f);
  __hip_bfloat16* dst = out + (size_t)row * HID_;
#pragma unroll
  for (int i = 0; i < 4; i++) {
    int c = i * 256 + tid;
    dst[c] = __float2bfloat16((x[i] - mu) * rs * ldin(gamma, c, md) + ldin(beta, c, md));
  }
}

__global__ __launch_bounds__(256) void ln_q_kernel(
    const void* __restrict__ qry,
    const void* __restrict__ gamma, const void* __restrict__ beta,
    __hip_bfloat16* __restrict__ out, const int* __restrict__ mode) {
  const int md = *mode;
  const int row = blockIdx.x;  // 0..B*Q-1
  const size_t base = (size_t)row * HID_;
  const int tid = threadIdx.x;
  float x[4];
  float s = 0.f, ss = 0.f;
#pragma unroll
  for (int i = 0; i < 4; i++) {
    x[i] = ldin(qry, base + i * 256 + tid, md);
    s += x[i]; ss += x[i] * x[i];
  }
#pragma unroll
  for (int o = 32; o > 0; o >>= 1) { s += __shfl_down(s, o); ss += __shfl_down(ss, o); }
  __shared__ float red[8];
  if ((tid & 63) == 0) { red[(tid >> 6) * 2] = s; red[(tid >> 6) * 2 + 1] = ss; }
  __syncthreads();
  float ts = 0.f, tss = 0.f;
#pragma unroll
  for (int i = 0; i < 4; i++) { ts += red[i * 2]; tss += red[i * 2 + 1]; }
  const float mu = ts * (1.f / 1024.f);
  const float var = tss * (1.f / 1024.f) - mu * mu;
  const float rs = rsqrtf(var + 1e-3f);
  __hip_bfloat16* dst = out + (size_t)row * HID_;
#pragma unroll
  for (int i = 0; i < 4; i++) {
    int c = i * 256 + tid;
    dst[c] = __float2bfloat16((x[i] - mu) * rs * ldin(gamma, c, md) + ldin(beta, c, md));
  }
}

// ---------------- sinusoidal position embedding, positions K-1..0 ----------------
__global__ __launch_bounds__(256) void posemb_kernel(__hip_bfloat16* __restrict__ pe) {
  const int p = blockIdx.x;
  const float pos = (float)(KL_ - 1 - p);
  const int tid = threadIdx.x;
#pragma unroll
  for (int i = 0; i < 4; i++) {
    int c = tid * 4 + i;
    int f = (c < 512) ? c : c - 512;
    float invf = powf(10000.0f, -(float)f * (1.0f / 512.0f));
    float a = pos * invf;
    float v = (c < 512) ? sinf(a) : cosf(a);
    pe[(size_t)p * HID_ + c] = __float2bfloat16(v);
  }
}

// ---------------- GEMM core: C = A @ BT^T (both bf16, K=1024), 128x128 tile ----------------
// writes bf16 always (internal); gemm_out variant writes d_out per mode.
template <int WRITE_MODE_SWITCH>
__device__ __forceinline__ void gemm_body(const __hip_bfloat16* __restrict__ A,
                                          const __hip_bfloat16* __restrict__ BT,
                                          void* __restrict__ C, int md) {
  __shared__ __attribute__((aligned(16))) __hip_bfloat16 sA[128 * 32];
  __shared__ __attribute__((aligned(16))) __hip_bfloat16 sB[128 * 32];
  const int tid = threadIdx.x;
  const int lane = tid & 63;
  const int w = tid >> 6;
  const int quad = lane >> 4, l16 = lane & 15;
  const int m0 = blockIdx.x * 128;
  const int n0 = blockIdx.y * 128;
  const int wm = (w >> 1) * 64, wn = (w & 1) * 64;
  const f32x4 fz = {0.f, 0.f, 0.f, 0.f};

  f32x4 acc[4][4];
#pragma unroll
  for (int i = 0; i < 4; i++)
#pragma unroll
    for (int j = 0; j < 4; j++) acc[i][j] = fz;

  for (int kk = 0; kk < HID_ / 32; kk++) {
    const int k0 = kk * 32;
    short8 ar[2], br[2];
#pragma unroll
    for (int t = 0; t < 2; t++) {
      int c = (w * 2 + t) * 64 + lane;
      int row = c >> 2;
      int cid = (c & 3) ^ (row & 3);
      ar[t] = *(const short8*)(A + (size_t)(m0 + row) * HID_ + k0 + cid * 8);
      br[t] = *(const short8*)(BT + (size_t)(n0 + row) * HID_ + k0 + cid * 8);
    }
    __syncthreads();
#pragma unroll
    for (int t = 0; t < 2; t++) {
      int c = (w * 2 + t) * 64 + lane;
      *(short8*)((char*)sA + c * 16) = ar[t];
      *(short8*)((char*)sB + c * 16) = br[t];
    }
    __syncthreads();
    short8 af[4], bf[4];
#pragma unroll
    for (int mt = 0; mt < 4; mt++) {
      int r = wm + mt * 16 + l16;
      af[mt] = *(const short8*)((const char*)sA + r * 64 + ((quad ^ (r & 3)) * 16));
    }
#pragma unroll
    for (int nt = 0; nt < 4; nt++) {
      int r = wn + nt * 16 + l16;
      bf[nt] = *(const short8*)((const char*)sB + r * 64 + ((quad ^ (r & 3)) * 16));
    }
#pragma unroll
    for (int mt = 0; mt < 4; mt++)
#pragma unroll
      for (int nt = 0; nt < 4; nt++)
        acc[mt][nt] = __builtin_amdgcn_mfma_f32_16x16x32_bf16(af[mt], bf[nt], acc[mt][nt], 0, 0, 0);
  }
#pragma unroll
  for (int mt = 0; mt < 4; mt++)
#pragma unroll
    for (int nt = 0; nt < 4; nt++)
#pragma unroll
      for (int rg = 0; rg < 4; rg++) {
        int r = m0 + wm + mt * 16 + quad * 4 + rg;
        int cc = n0 + wn + nt * 16 + l16;
        size_t idx = (size_t)r * HID_ + cc;
        if (WRITE_MODE_SWITCH && md) ((float*)C)[idx] = acc[mt][nt][rg];
        else ((__hip_bfloat16*)C)[idx] = __float2bfloat16(acc[mt][nt][rg]);
      }
}

__global__ __launch_bounds__(256) void gemm_bt128(const __hip_bfloat16* __restrict__ A,
                                                  const __hip_bfloat16* __restrict__ BT,
                                                  __hip_bfloat16* __restrict__ C) {
  gemm_body<0>(A, BT, (void*)C, 0);
}

__global__ __launch_bounds__(256) void gemm_out(const __hip_bfloat16* __restrict__ A,
                                                const __hip_bfloat16* __restrict__ BT,
                                                void* __restrict__ C,
                                                const int* __restrict__ mode) {
  gemm_body<1>(A, BT, C, *mode);
}

// ---------------- bias dots: c[b][h][j] = rwb_h . k_j ; e[h][p] = rrb_h . rel_p ----------------
__global__ __launch_bounds__(256) void cbias_kernel(const __hip_bfloat16* __restrict__ kp,
                                                    const void* __restrict__ rwb,
                                                    float* __restrict__ cb,
                                                    const int* __restrict__ mode) {
  const int md = *mode;
  const int idx = blockIdx.x * 256 + threadIdx.x;  // B*H*KL
  const int j = idx % KL_;
  const int h = (idx / KL_) % H_;
  const int b = idx / (KL_ * H_);
  const __hip_bfloat16* kr = kp + ((size_t)b * KL_ + j) * HID_ + h * D_;
  float s = 0.f;
#pragma unroll 8
  for (int d = 0; d < D_; d++) s += __bfloat162float(kr[d]) * ldin(rwb, h * D_ + d, md);
  cb[idx] = s;
}

__global__ __launch_bounds__(256) void ebias_kernel(const __hip_bfloat16* __restrict__ relp,
                                                    const void* __restrict__ rrb,
                                                    float* __restrict__ eb,
                                                    const int* __restrict__ mode) {
  const int md = *mode;
  const int idx = blockIdx.x * 256 + threadIdx.x;  // H*KL
  const int p = idx % KL_;
  const int h = idx / KL_;
  const __hip_bfloat16* rr = relp + (size_t)p * HID_ + h * D_;
  float s = 0.f;
#pragma unroll 8
  for (int d = 0; d < D_; d++) s += __bfloat162float(rr[d]) * ldin(rrb, h * D_ + d, md);
  eb[idx] = s;
}

// ---------------- fused relative attention ----------------
// grid (Q/64, H, B), block 256 (4 waves). Each wave owns a 16-row strip.
__global__ __launch_bounds__(256, 2) void attn_kernel(
    const __hip_bfloat16* __restrict__ qp, const __hip_bfloat16* __restrict__ kp,
    const __hip_bfloat16* __restrict__ vpt, const __hip_bfloat16* __restrict__ relp,
    const float* __restrict__ cb, const float* __restrict__ eb,
    const void* __restrict__ spanv, __hip_bfloat16* __restrict__ attn_out,
    const int* __restrict__ mode) {
  const int md = *mode;
  const int i0 = blockIdx.x * RT_;
  const int h = blockIdx.y;
  const int b = blockIdx.z;
  const int tid = threadIdx.x;
  const int lane = tid & 63;
  const int w = tid >> 6;
  const int quad = lane >> 4, l16 = lane & 15;
  const f32x4 fz = {0.f, 0.f, 0.f, 0.f};

  __shared__ __attribute__((aligned(16))) __hip_bfloat16 sq[RT_ * 64];    // [64][64]
  __shared__ __attribute__((aligned(16))) __hip_bfloat16 sk[WT_ * 64];    // [128][64]; reused as P [64][128]
  __shared__ __attribute__((aligned(16))) __hip_bfloat16 svt[64 * WT_];   // [64][128]
  __shared__ __attribute__((aligned(16))) __hip_bfloat16 srel[64 * 64];   // [64][64]
  __shared__ __attribute__((aligned(16))) __hip_bfloat16 sT[64 * 64];     // [64][64]

  const __hip_bfloat16* qbase = qp + ((size_t)(b * Q_ + i0)) * HID_ + h * D_;
#pragma unroll
  for (int t = 0; t < 2; t++) {
    int c = (w * 2 + t) * 64 + lane;
    int row = c >> 3;
    int cid = (c & 7) ^ (row & 7);
    short8 v = *(const short8*)(qbase + (size_t)row * HID_ + cid * 8);
    *(short8*)((char*)sq + c * 16) = v;
  }
  __syncthreads();
  short8 qf[2];
#pragma unroll
  for (int ks = 0; ks < 2; ks++) {
    int r = w * 16 + l16;
    int cid = (ks * 4 + quad) ^ (r & 7);
    qf[ks] = *(const short8*)((const char*)sq + r * 128 + cid * 16);
  }

  float mrow[4], lrow[4], lmrow[4];
#pragma unroll
  for (int rg = 0; rg < 4; rg++) { mrow[rg] = -3e38f; lrow[rg] = 0.f; lmrow[rg] = 0.f; }
  f32x4 oacc[4];
#pragma unroll
  for (int dt = 0; dt < 4; dt++) oacc[dt] = fz;

  const __hip_bfloat16* kbase = kp + (size_t)b * KL_ * HID_ + h * D_;
  const __hip_bfloat16* vtbase = vpt + ((size_t)(b * H_ + h)) * D_ * KL_;
  const float* cbb = cb + (size_t)(b * H_ + h) * KL_;
  const float* ebb = eb + (size_t)h * KL_;
  const float sv = ldin(spanv, h, md);

  const int ntiles = ((M_ + i0 + RT_ - 1) >> 7) + 1;

  for (int kt = 0; kt < ntiles; kt++) {
    const int j0 = kt * WT_;
    const int pbase = Q_ - RT_ - i0 + j0;  // p = pbase + (63-di) + jj, always >= 0

    // global loads for this tile (regs), stores after the barrier
    short8 kr[4], vr[4], rr[2];
#pragma unroll
    for (int t = 0; t < 4; t++) {
      int c = (w * 4 + t) * 64 + lane;
      int row = c >> 3;
      int cid = (c & 7) ^ (row & 7);
      kr[t] = *(const short8*)(kbase + (size_t)(j0 + row) * HID_ + cid * 8);
    }
#pragma unroll
    for (int t = 0; t < 4; t++) {
      int c = (w * 4 + t) * 64 + lane;
      int row = c >> 4;
      int cid = (c & 15) ^ (row & 15);
      vr[t] = *(const short8*)(vtbase + (size_t)row * KL_ + j0 + cid * 8);
    }
#pragma unroll
    for (int t = 0; t < 2; t++) {
      int c = (w * 2 + t) * 64 + lane;
      int row = c >> 3;
      int cid = (c & 7) ^ (row & 7);
      int p = pbase + row; p = p < KL_ ? p : KL_ - 1;  // clamped rows feed only masked cols
      rr[t] = *(const short8*)(relp + (size_t)p * HID_ + h * D_ + cid * 8);
    }

    f32x4 S[8];
#pragma unroll
    for (int nt = 0; nt < 8; nt++) S[nt] = fz;

    __syncthreads();  // previous iteration's LDS consumers done
#pragma unroll
    for (int t = 0; t < 4; t++) { int c = (w * 4 + t) * 64 + lane; *(short8*)((char*)sk + c * 16) = kr[t]; }
#pragma unroll
    for (int t = 0; t < 4; t++) { int c = (w * 4 + t) * 64 + lane; *(short8*)((char*)svt + c * 16) = vr[t]; }
#pragma unroll
    for (int t = 0; t < 2; t++) { int c = (w * 2 + t) * 64 + lane; *(short8*)((char*)srel + c * 16) = rr[t]; }
    __syncthreads();

    // AD = q . k^T
#pragma unroll
    for (int ks = 0; ks < 2; ks++)
#pragma unroll
      for (int nt = 0; nt < 8; nt++) {
        int r = nt * 16 + l16;
        int cid = (ks * 4 + quad) ^ (r & 7);
        short8 bfv = *(const short8*)((const char*)sk + r * 128 + cid * 16);
        S[nt] = __builtin_amdgcn_mfma_f32_16x16x32_bf16(qf[ks], bfv, S[nt], 0, 0, 0);
      }

    // shifted-T band in 3 chunks of 64 cols; t = (63-di)+jj in [0,191)
    for (int ch = 0; ch < 3; ch++) {
      f32x4 T[4];
#pragma unroll
      for (int nt = 0; nt < 4; nt++) T[nt] = fz;
#pragma unroll
      for (int ks = 0; ks < 2; ks++)
#pragma unroll
        for (int nt = 0; nt < 4; nt++) {
          int r = nt * 16 + l16;
          int cid = (ks * 4 + quad) ^ (r & 7);
          short8 bfv = *(const short8*)((const char*)srel + r * 128 + cid * 16);
          T[nt] = __builtin_amdgcn_mfma_f32_16x16x32_bf16(qf[ks], bfv, T[nt], 0, 0, 0);
        }
      // preload next rel chunk into regs (stored after the barrier)
      short8 rn[2];
      if (ch < 2) {
#pragma unroll
        for (int t = 0; t < 2; t++) {
          int c = (w * 2 + t) * 64 + lane;
          int row = c >> 3;
          int cid = (c & 7) ^ (row & 7);
          int p = pbase + (ch + 1) * 64 + row; p = p < KL_ ? p : KL_ - 1;
          rn[t] = *(const short8*)(relp + (size_t)p * HID_ + h * D_ + cid * 8);
        }
      }
      // write T (+ e_p) to sT, bf16, swizzled
#pragma unroll
      for (int nt = 0; nt < 4; nt++)
#pragma unroll
        for (int rg = 0; rg < 4; rg++) {
          int di = w * 16 + quad * 4 + rg;
          int tc = nt * 16 + l16;
          int p = pbase + ch * 64 + tc;
          float e = ebb[p < KL_ ? p : KL_ - 1];
          int cid = (tc >> 3) ^ (di & 7);
          *(__hip_bfloat16*)((char*)sT + di * 128 + cid * 16 + (tc & 7) * 2) =
              __float2bfloat16(T[nt][rg] + e);
        }
      __syncthreads();  // sT visible; all srel MFMA reads done block-wide
      if (ch < 2) {
#pragma unroll
        for (int t = 0; t < 2; t++) {
          int c = (w * 2 + t) * 64 + lane;
          *(short8*)((char*)srel + c * 16) = rn[t];
        }
      }
      // gather with per-row shift
#pragma unroll
      for (int nt = 0; nt < 8; nt++)
#pragma unroll
        for (int rg = 0; rg < 4; rg++) {
          int di = w * 16 + quad * 4 + rg;
          int jj = nt * 16 + l16;
          int tt = 63 - di + jj - ch * 64;
          if (tt >= 0 && tt < 64) {
            int cid = (tt >> 3) ^ (di & 7);
            float tv = __bfloat162float(
                *(const __hip_bfloat16*)((const char*)sT + di * 128 + cid * 16 + (tt & 7) * 2));
            S[nt][rg] += tv;
          }
        }
      __syncthreads();  // srel stores visible; sT reads done before next overwrite
    }

    // logits = (AD + T' + c_j)/64, causal mask; online softmax
    float mnew[4];
#pragma unroll
    for (int rg = 0; rg < 4; rg++) mnew[rg] = mrow[rg];
#pragma unroll
    for (int nt = 0; nt < 8; nt++) {
      int jj = nt * 16 + l16;
      int j = j0 + jj;
      float cbv = cbb[j];
#pragma unroll
      for (int rg = 0; rg < 4; rg++) {
        int i = i0 + w * 16 + quad * 4 + rg;
        float v = (S[nt][rg] + cbv) * (1.0f / 64.0f);
        if (j - i > M_) v = -1e30f;  // exp -> exactly 0, same as ref's -1e9 bias
        S[nt][rg] = v;
        mnew[rg] = fmaxf(mnew[rg], v);
      }
    }
#pragma unroll
    for (int o = 1; o < 16; o <<= 1)
#pragma unroll
      for (int rg = 0; rg < 4; rg++) mnew[rg] = fmaxf(mnew[rg], __shfl_xor(mnew[rg], o, 64));
    float alpha[4];
#pragma unroll
    for (int rg = 0; rg < 4; rg++) {
      alpha[rg] = expf(mrow[rg] - mnew[rg]);
      mrow[rg] = mnew[rg];
      lrow[rg] *= alpha[rg];
      lmrow[rg] *= alpha[rg];
    }
#pragma unroll
    for (int dt = 0; dt < 4; dt++)
#pragma unroll
      for (int rg = 0; rg < 4; rg++) oacc[dt][rg] *= alpha[rg];

    // P = exp(S - m); span-masked P into sk (reused as P buffer [64][128])
#pragma unroll
    for (int nt = 0; nt < 8; nt++) {
      int jj = nt * 16 + l16;
      int j = j0 + jj;
      float mk;
      if (j < M_) mk = 1.f;
      else {
        float t0 = (float)(j - M_) + sv * (float)Q_;
        mk = fminf(fmaxf(t0 * (1.0f / 33.0f), 0.f), 1.f);
      }
#pragma unroll
      for (int rg = 0; rg < 4; rg++) {
        float pv = expf(S[nt][rg] - mrow[rg]);
        lrow[rg] += pv;
        float pm = pv * mk;
        lmrow[rg] += pm;
        int di = w * 16 + quad * 4 + rg;
        int cid = (jj >> 3) ^ (di & 15);
        *(__hip_bfloat16*)((char*)sk + di * 256 + cid * 16 + (jj & 7) * 2) = __float2bfloat16(pm);
      }
    }
    __syncthreads();
    // PV: oacc[m=i][n=d] += P[i][j] * V[j][d]  (B-frag from V^T rows d)
#pragma unroll
    for (int ks = 0; ks < 4; ks++) {
      int ar = w * 16 + l16;
      int acid = (ks * 4 + quad) ^ (ar & 15);
      short8 af = *(const short8*)((const char*)sk + ar * 256 + acid * 16);
#pragma unroll
      for (int dt = 0; dt < 4; dt++) {
        int br = dt * 16 + l16;
        int bcid = (ks * 4 + quad) ^ (br & 15);
        short8 bfv = *(const short8*)((const char*)svt + br * 256 + bcid * 16);
        oacc[dt] = __builtin_amdgcn_mfma_f32_16x16x32_bf16(af, bfv, oacc[dt], 0, 0, 0);
      }
    }
  }

#pragma unroll
  for (int o = 1; o < 16; o <<= 1)
#pragma unroll
    for (int rg = 0; rg < 4; rg++) {
      lrow[rg] += __shfl_xor(lrow[rg], o, 64);
      lmrow[rg] += __shfl_xor(lmrow[rg], o, 64);
    }
#pragma unroll
  for (int dt = 0; dt < 4; dt++)
#pragma unroll
    for (int rg = 0; rg < 4; rg++) {
      int i = i0 + w * 16 + quad * 4 + rg;
      float denom = lmrow[rg] + 1e-8f * lrow[rg];
      float ov = oacc[dt][rg] / denom;
      attn_out[((size_t)(b * Q_ + i)) * HID_ + h * D_ + dt * 16 + l16] = __float2bfloat16(ov);
    }
}

// ---------------- launcher ----------------
extern "C" void kernel_launch(void* const* d_in, const int* in_sizes, int n_in,
                              void* d_out, int out_size, void* d_ws, size_t ws_size,
                              hipStream_t stream) {
  const void* query  = d_in[0];
  const void* memory = d_in[1];
  const void* Wq = d_in[2];
  const void* Wk = d_in[3];
  const void* Wv = d_in[4];
  const void* Wo = d_in[5];
  const void* Wr = d_in[6];
  const void* gmem = d_in[7];
  const void* bmem = d_in[8];
  const void* gq = d_in[9];
  const void* bq = d_in[10];
  const void* rwb = d_in[11];
  const void* rrb = d_in[12];
  const void* spanv = d_in[13];

  char* ws = (char*)d_ws;
  size_t off = 0;
  auto alloc = [&](size_t bytes) -> char* {
    char* p = ws + off;
    off += (bytes + 255) & ~(size_t)255;
    return p;
  };
  int* flag = (int*)alloc(256);
  const size_t SZ_W = (size_t)HID_ * HID_ * 2;
  __hip_bfloat16* wqT = (__hip_bfloat16*)alloc(SZ_W);
  __hip_bfloat16* wkT = (__hip_bfloat16*)alloc(SZ_W);
  __hip_bfloat16* wvT = (__hip_bfloat16*)alloc(SZ_W);
  __hip_bfloat16* wrT = (__hip_bfloat16*)alloc(SZ_W);
  __hip_bfloat16* woT = (__hip_bfloat16*)alloc(SZ_W);
  __hip_bfloat16* kvln = (__hip_bfloat16*)alloc((size_t)B_ * KL_ * HID_ * 2);
  __hip_bfloat16* qln  = (__hip_bfloat16*)alloc((size_t)B_ * Q_ * HID_ * 2);
  __hip_bfloat16* pe   = (__hip_bfloat16*)alloc((size_t)KL_ * HID_ * 2);
  __hip_bfloat16* qpb  = (__hip_bfloat16*)alloc((size_t)B_ * Q_ * HID_ * 2);
  __hip_bfloat16* kpb  = (__hip_bfloat16*)alloc((size_t)B_ * KL_ * HID_ * 2);
  __hip_bfloat16* vpb  = (__hip_bfloat16*)alloc((size_t)B_ * KL_ * HID_ * 2);
  __hip_bfloat16* relp = (__hip_bfloat16*)alloc((size_t)KL_ * HID_ * 2);
  __hip_bfloat16* aout = (__hip_bfloat16*)alloc((size_t)B_ * Q_ * HID_ * 2);
  float* cbf = (float*)alloc((size_t)B_ * H_ * KL_ * 4);
  float* ebf = (float*)alloc((size_t)H_ * KL_ * 4);
  __hip_bfloat16* vptb = kvln;  // alias: kvln dead after the k/v projection GEMMs

  dim3 tb(256);
  detect_kernel<<<dim3(1), tb, 0, stream>>>((const unsigned int*)query, flag);

  wt_kernel<<<dim3(16, 16), tb, 0, stream>>>(Wq, wqT, flag);
  wt_kernel<<<dim3(16, 16), tb, 0, stream>>>(Wk, wkT, flag);
  wt_kernel<<<dim3(16, 16), tb, 0, stream>>>(Wv, wvT, flag);
  wt_kernel<<<dim3(16, 16), tb, 0, stream>>>(Wr, wrT, flag);
  wt_kernel<<<dim3(16, 16), tb, 0, stream>>>(Wo, woT, flag);

  ln_kv_kernel<<<dim3(B_ * KL_), tb, 0, stream>>>(memory, query, gmem, bmem, kvln, flag);
  ln_q_kernel<<<dim3(B_ * Q_), tb, 0, stream>>>(query, gq, bq, qln, flag);
  posemb_kernel<<<dim3(KL_), tb, 0, stream>>>(pe);

  gemm_bt128<<<dim3(B_ * Q_ / 128, HID_ / 128), tb, 0, stream>>>(qln, wqT, qpb);
  gemm_bt128<<<dim3(B_ * KL_ / 128, HID_ / 128), tb, 0, stream>>>(kvln, wkT, kpb);
  gemm_bt128<<<dim3(B_ * KL_ / 128, HID_ / 128), tb, 0, stream>>>(kvln, wvT, vpb);
  gemm_bt128<<<dim3(KL_ / 128, HID_ / 128), tb, 0, stream>>>(pe, wrT, relp);

  vpt_kernel<<<dim3(KL_ / 64, B_ * H_), tb, 0, stream>>>(vpb, vptb);
  cbias_kernel<<<dim3(B_ * H_ * KL_ / 256), tb, 0, stream>>>(kpb, rwb, cbf, flag);
  ebias_kernel<<<dim3(H_ * KL_ / 256), tb, 0, stream>>>(relp, rrb, ebf, flag);

  attn_kernel<<<dim3(Q_ / RT_, H_, B_), tb, 0, stream>>>(qpb, kpb, vptb, relp, cbf, ebf, spanv, aout, flag);

  gemm_out<<<dim3(B_ * Q_ / 128, HID_ / 128), tb, 0, stream>>>(aout, woT, d_out, flag);

  (void)in_sizes; (void)n_in; (void)out_size; (void)ws_size;
}

// Round 3
// 1213.230 us; speedup vs baseline: 1.0156x; 1.0156x over previous
//
#include <hip/hip_runtime.h>
#include <hip/hip_bf16.h>
#include <math.h>

#define B_   2
#define Q_   2048
#define M_   2048
#define H_   16
#define D_   64
#define HID_ 1024
#define KL_  4096
#define RT_  64      // q rows per attention block
#define WT_  128     // k cols per attention tile

typedef short short8 __attribute__((ext_vector_type(8)));
typedef float f32x4 __attribute__((ext_vector_type(4)));

// read input element i as float, md=1 -> fp32 buffer, md=0 -> bf16 buffer
__device__ __forceinline__ float ldin(const void* p, size_t i, int md) {
  return md ? ((const float*)p)[i] : __bfloat162float(((const __hip_bfloat16*)p)[i]);
}

// ---------------- dtype detector: writes 1 if inputs are fp32, else 0 ----------------
__global__ __launch_bounds__(256) void detect_kernel(const unsigned int* __restrict__ q,
                                                     int* __restrict__ flag) {
  __shared__ int cnt;
  if (threadIdx.x == 0) cnt = 0;
  __syncthreads();
  int ins = 0;
#pragma unroll
  for (int i = 0; i < 4; i++) {
    unsigned int u = q[threadIdx.x * 4 + i];
    int e0 = (int)((u >> 7) & 0xffu);
    int e1 = (int)((u >> 23) & 0xffu);
    if (e0 == 0xff || e0 < 102 || e0 > 140) ins++;
    if (e1 == 0xff || e1 < 102 || e1 > 140) ins++;
  }
  atomicAdd(&cnt, ins);
  __syncthreads();
  if (threadIdx.x == 0) *flag = (cnt > 512) ? 1 : 0;
}

// ---------------- weight transpose: wt[n][k] = src[k][n], 1024x1024 ----------------
__global__ __launch_bounds__(256) void wt_kernel(const void* __restrict__ src,
                                                 __hip_bfloat16* __restrict__ wt,
                                                 const int* __restrict__ mode) {
  const int md = *mode;
  const int r0 = blockIdx.x * 64, c0 = blockIdx.y * 64;
  __shared__ __hip_bfloat16 t[64][65];
  const int tid = threadIdx.x;
  const int col = tid & 63, r4 = tid >> 6;
#pragma unroll
  for (int i = 0; i < 16; i++)
    t[r4 + i * 4][col] = __float2bfloat16(ldin(src, (size_t)(r0 + r4 + i * 4) * HID_ + c0 + col, md));
  __syncthreads();
#pragma unroll
  for (int i = 0; i < 16; i++)
    wt[(size_t)(c0 + r4 + i * 4) * HID_ + r0 + col] = t[col][r4 + i * 4];
}

// ---------------- V transpose: vpt[b][h][d][j] = vp[b*K+j][h*64+d] ----------------
__global__ __launch_bounds__(256) void vpt_kernel(const __hip_bfloat16* __restrict__ vp,
                                                  __hip_bfloat16* __restrict__ vpt) {
  const int jt = blockIdx.x * 64;
  const int bh = blockIdx.y;
  const int b = bh / H_, h = bh % H_;
  __shared__ __hip_bfloat16 t[64][65];
  const int tid = threadIdx.x;
  const int col = tid & 63, r4 = tid >> 6;
#pragma unroll
  for (int i = 0; i < 16; i++) {
    int j = r4 + i * 4;
    t[j][col] = vp[((size_t)b * KL_ + jt + j) * HID_ + h * D_ + col];
  }
  __syncthreads();
#pragma unroll
  for (int i = 0; i < 16; i++) {
    int d = r4 + i * 4;
    vpt[(((size_t)b * H_ + h) * D_ + d) * KL_ + jt + col] = t[col][d];
  }
}

// ---------------- LayerNorm over concat(memory, query) rows ----------------
__global__ __launch_bounds__(256) void ln_kv_kernel(
    const void* __restrict__ mem, const void* __restrict__ qry,
    const void* __restrict__ gamma, const void* __restrict__ beta,
    __hip_bfloat16* __restrict__ out, const int* __restrict__ mode) {
  const int md = *mode;
  const int row = blockIdx.x;  // 0..B*KL-1
  const int b = row / KL_, j = row % KL_;
  const void* src;
  size_t base;
  if (j < M_) { src = mem; base = ((size_t)b * M_ + j) * HID_; }
  else        { src = qry; base = ((size_t)b * Q_ + (j - M_)) * HID_; }
  const int tid = threadIdx.x;
  float x[4];
  float s = 0.f, ss = 0.f;
#pragma unroll
  for (int i = 0; i < 4; i++) {
    x[i] = ldin(src, base + i * 256 + tid, md);
    s += x[i]; ss += x[i] * x[i];
  }
#pragma unroll
  for (int o = 32; o > 0; o >>= 1) { s += __shfl_down(s, o); ss += __shfl_down(ss, o); }
  __shared__ float red[8];
  if ((tid & 63) == 0) { red[(tid >> 6) * 2] = s; red[(tid >> 6) * 2 + 1] = ss; }
  __syncthreads();
  float ts = 0.f, tss = 0.f;
#pragma unroll
  for (int i = 0; i < 4; i++) { ts += red[i * 2]; tss += red[i * 2 + 1]; }
  const float mu = ts * (1.f / 1024.f);
  const float var = tss * (1.f / 1024.f) - mu * mu;
  const float rs = rsqrtf(var + 1e-3f);
  __hip_bfloat16* dst = out + (size_t)row * HID_;
#pragma unroll
  for (int i = 0; i < 4; i++) {
    int c = i * 256 + tid;
    dst[c] = __float2bfloat16((x[i] - mu) * rs * ldin(gamma, c, md) + ldin(beta, c, md));
  }
}

__global__ __launch_bounds__(256) void ln_q_kernel(
    const void* __restrict__ qry,
    const void* __restrict__ gamma, const void* __restrict__ beta,
    __hip_bfloat16* __restrict__ out, const int* __restrict__ mode) {
  const int md = *mode;
  const int row = blockIdx.x;  // 0..B*Q-1
  const size_t base = (size_t)row * HID_;
  const int tid = threadIdx.x;
  float x[4];
  float s = 0.f, ss = 0.f;
#pragma unroll
  for (int i = 0; i < 4; i++) {
    x[i] = ldin(qry, base + i * 256 + tid, md);
    s += x[i]; ss += x[i] * x[i];
  }
#pragma unroll
  for (int o = 32; o > 0; o >>= 1) { s += __shfl_down(s, o); ss += __shfl_down(ss, o); }
  __shared__ float red[8];
  if ((tid & 63) == 0) { red[(tid >> 6) * 2] = s; red[(tid >> 6) * 2 + 1] = ss; }
  __syncthreads();
  float ts = 0.f, tss = 0.f;
#pragma unroll
  for (int i = 0; i < 4; i++) { ts += red[i * 2]; tss += red[i * 2 + 1]; }
  const float mu = ts * (1.f / 1024.f);
  const float var = tss * (1.f / 1024.f) - mu * mu;
  const float rs = rsqrtf(var + 1e-3f);
  __hip_bfloat16* dst = out + (size_t)row * HID_;
#pragma unroll
  for (int i = 0; i < 4; i++) {
    int c = i * 256 + tid;
    dst[c] = __float2bfloat16((x[i] - mu) * rs * ldin(gamma, c, md) + ldin(beta, c, md));
  }
}

// ---------------- sinusoidal position embedding, positions K-1..0 ----------------
__global__ __launch_bounds__(256) void posemb_kernel(__hip_bfloat16* __restrict__ pe) {
  const int p = blockIdx.x;
  const float pos = (float)(KL_ - 1 - p);
  const int tid = threadIdx.x;
#pragma unroll
  for (int i = 0; i < 4; i++) {
    int c = tid * 4 + i;
    int f = (c < 512) ? c : c - 512;
    float invf = powf(10000.0f, -(float)f * (1.0f / 512.0f));
    float a = pos * invf;
    float v = (c < 512) ? sinf(a) : cosf(a);
    pe[(size_t)p * HID_ + c] = __float2bfloat16(v);
  }
}

// ---------------- GEMM core: C = A @ BT^T (both bf16, K=1024), 128x128 tile ----------------
template <int WRITE_MODE_SWITCH>
__device__ __forceinline__ void gemm_body(const __hip_bfloat16* __restrict__ A,
                                          const __hip_bfloat16* __restrict__ BT,
                                          void* __restrict__ C, int md) {
  __shared__ __attribute__((aligned(16))) __hip_bfloat16 sA[128 * 32];
  __shared__ __attribute__((aligned(16))) __hip_bfloat16 sB[128 * 32];
  const int tid = threadIdx.x;
  const int lane = tid & 63;
  const int w = tid >> 6;
  const int quad = lane >> 4, l16 = lane & 15;
  const int m0 = blockIdx.x * 128;
  const int n0 = blockIdx.y * 128;
  const int wm = (w >> 1) * 64, wn = (w & 1) * 64;
  const f32x4 fz = {0.f, 0.f, 0.f, 0.f};

  f32x4 acc[4][4];
#pragma unroll
  for (int i = 0; i < 4; i++)
#pragma unroll
    for (int j = 0; j < 4; j++) acc[i][j] = fz;

  for (int kk = 0; kk < HID_ / 32; kk++) {
    const int k0 = kk * 32;
    short8 ar[2], br[2];
#pragma unroll
    for (int t = 0; t < 2; t++) {
      int c = (w * 2 + t) * 64 + lane;
      int row = c >> 2;
      int cid = (c & 3) ^ (row & 3);
      ar[t] = *(const short8*)(A + (size_t)(m0 + row) * HID_ + k0 + cid * 8);
      br[t] = *(const short8*)(BT + (size_t)(n0 + row) * HID_ + k0 + cid * 8);
    }
    __syncthreads();
#pragma unroll
    for (int t = 0; t < 2; t++) {
      int c = (w * 2 + t) * 64 + lane;
      *(short8*)((char*)sA + c * 16) = ar[t];
      *(short8*)((char*)sB + c * 16) = br[t];
    }
    __syncthreads();
    short8 af[4], bf[4];
#pragma unroll
    for (int mt = 0; mt < 4; mt++) {
      int r = wm + mt * 16 + l16;
      af[mt] = *(const short8*)((const char*)sA + r * 64 + ((quad ^ (r & 3)) * 16));
    }
#pragma unroll
    for (int nt = 0; nt < 4; nt++) {
      int r = wn + nt * 16 + l16;
      bf[nt] = *(const short8*)((const char*)sB + r * 64 + ((quad ^ (r & 3)) * 16));
    }
#pragma unroll
    for (int mt = 0; mt < 4; mt++)
#pragma unroll
      for (int nt = 0; nt < 4; nt++)
        acc[mt][nt] = __builtin_amdgcn_mfma_f32_16x16x32_bf16(af[mt], bf[nt], acc[mt][nt], 0, 0, 0);
  }
#pragma unroll
  for (int mt = 0; mt < 4; mt++)
#pragma unroll
    for (int nt = 0; nt < 4; nt++)
#pragma unroll
      for (int rg = 0; rg < 4; rg++) {
        int r = m0 + wm + mt * 16 + quad * 4 + rg;
        int cc = n0 + wn + nt * 16 + l16;
        size_t idx = (size_t)r * HID_ + cc;
        if (WRITE_MODE_SWITCH && md) ((float*)C)[idx] = acc[mt][nt][rg];
        else ((__hip_bfloat16*)C)[idx] = __float2bfloat16(acc[mt][nt][rg]);
      }
}

__global__ __launch_bounds__(256) void gemm_bt128(const __hip_bfloat16* __restrict__ A,
                                                  const __hip_bfloat16* __restrict__ BT,
                                                  __hip_bfloat16* __restrict__ C) {
  gemm_body<0>(A, BT, (void*)C, 0);
}

__global__ __launch_bounds__(256) void gemm_out(const __hip_bfloat16* __restrict__ A,
                                                const __hip_bfloat16* __restrict__ BT,
                                                void* __restrict__ C,
                                                const int* __restrict__ mode) {
  gemm_body<1>(A, BT, C, *mode);
}

// ---------------- bias dots: c[b][h][j] = rwb_h . k_j ; e[h][p] = rrb_h . rel_p ----------------
__global__ __launch_bounds__(256) void cbias_kernel(const __hip_bfloat16* __restrict__ kp,
                                                    const void* __restrict__ rwb,
                                                    float* __restrict__ cb,
                                                    const int* __restrict__ mode) {
  const int md = *mode;
  const int idx = blockIdx.x * 256 + threadIdx.x;  // B*H*KL
  const int j = idx % KL_;
  const int h = (idx / KL_) % H_;
  const int b = idx / (KL_ * H_);
  const __hip_bfloat16* kr = kp + ((size_t)b * KL_ + j) * HID_ + h * D_;
  float s = 0.f;
#pragma unroll 8
  for (int d = 0; d < D_; d++) s += __bfloat162float(kr[d]) * ldin(rwb, h * D_ + d, md);
  cb[idx] = s;
}

__global__ __launch_bounds__(256) void ebias_kernel(const __hip_bfloat16* __restrict__ relp,
                                                    const void* __restrict__ rrb,
                                                    float* __restrict__ eb,
                                                    const int* __restrict__ mode) {
  const int md = *mode;
  const int idx = blockIdx.x * 256 + threadIdx.x;  // H*KL
  const int p = idx % KL_;
  const int h = idx / KL_;
  const __hip_bfloat16* rr = relp + (size_t)p * HID_ + h * D_;
  float s = 0.f;
#pragma unroll 8
  for (int d = 0; d < D_; d++) s += __bfloat162float(rr[d]) * ldin(rrb, h * D_ + d, md);
  eb[idx] = s;
}

// ---------------- fused relative attention, software-pipelined ----------------
// grid (Q/64, H, B), block 256 (4 waves). Each wave owns a 16-row strip.
// Pipeline: regs hold tile kt+1's globals while LDS holds tile kt. 4 barriers/tile.
__global__ __launch_bounds__(256, 2) void attn_kernel(
    const __hip_bfloat16* __restrict__ qp, const __hip_bfloat16* __restrict__ kp,
    const __hip_bfloat16* __restrict__ vpt, const __hip_bfloat16* __restrict__ relp,
    const float* __restrict__ cb, const float* __restrict__ eb,
    const void* __restrict__ spanv, __hip_bfloat16* __restrict__ attn_out,
    const int* __restrict__ mode) {
  const int md = *mode;
  const int i0 = blockIdx.x * RT_;
  const int h = blockIdx.y;
  const int b = blockIdx.z;
  const int tid = threadIdx.x;
  const int lane = tid & 63;
  const int w = tid >> 6;
  const int quad = lane >> 4, l16 = lane & 15;
  const f32x4 fz = {0.f, 0.f, 0.f, 0.f};

  __shared__ __attribute__((aligned(16))) __hip_bfloat16 sq[RT_ * 64];     // 8K
  __shared__ __attribute__((aligned(16))) __hip_bfloat16 sk[WT_ * 64];     // 16K: K tile, then P[64][128]
  __shared__ __attribute__((aligned(16))) __hip_bfloat16 srel[192 * 64];   // 24K: rel band; later aliased as V^T[64][128]
  __shared__ __attribute__((aligned(16))) __hip_bfloat16 sTs[64 * 136];    // 17K: shifted T, row stride 136 halves (272B, 2-way max)
  __shared__ float se[192];
  __shared__ float sc[128];

  // ---- stage q once ----
  const __hip_bfloat16* qbase = qp + ((size_t)(b * Q_ + i0)) * HID_ + h * D_;
#pragma unroll
  for (int t = 0; t < 2; t++) {
    int c = (w * 2 + t) * 64 + lane;
    int row = c >> 3;
    int cid = (c & 7) ^ (row & 7);
    short8 v = *(const short8*)(qbase + (size_t)row * HID_ + cid * 8);
    *(short8*)((char*)sq + c * 16) = v;
  }
  __syncthreads();
  short8 qf[2];
#pragma unroll
  for (int ks = 0; ks < 2; ks++) {
    int r = w * 16 + l16;
    int cid = (ks * 4 + quad) ^ (r & 7);
    qf[ks] = *(const short8*)((const char*)sq + r * 128 + cid * 16);
  }

  float mrow[4], lrow[4], lmrow[4];
#pragma unroll
  for (int rg = 0; rg < 4; rg++) { mrow[rg] = -3e38f; lrow[rg] = 0.f; lmrow[rg] = 0.f; }
  f32x4 oacc[4];
#pragma unroll
  for (int dt = 0; dt < 4; dt++) oacc[dt] = fz;

  const __hip_bfloat16* kbase = kp + (size_t)b * KL_ * HID_ + h * D_;
  const __hip_bfloat16* vtbase = vpt + ((size_t)(b * H_ + h)) * D_ * KL_;
  const float* cbb = cb + (size_t)(b * H_ + h) * KL_;
  const float* ebb = eb + (size_t)h * KL_;
  const float sv = ldin(spanv, h, md);
  const int pb0 = Q_ - RT_ - i0;  // pbase at j0=0 (always >= 0)

  const int ntiles = ((M_ + i0 + RT_ - 1) >> 7) + 1;

  // ---- preload tile 0 into regs ----
  short8 krg[4], rrg[6], vcur[4], vnxt[4];
  float eng = 0.f, cng = 0.f;
  {
#pragma unroll
    for (int t = 0; t < 4; t++) {
      int c = (w * 4 + t) * 64 + lane;
      int row = c >> 3;
      int cid = (c & 7) ^ (row & 7);
      krg[t] = *(const short8*)(kbase + (size_t)row * HID_ + cid * 8);
    }
#pragma unroll
    for (int t = 0; t < 6; t++) {
      int c = t * 256 + tid;
      int row = c >> 3;
      int cid = (c & 7) ^ (row & 7);
      int p = pb0 + row; p = p < KL_ ? p : KL_ - 1;
      rrg[t] = *(const short8*)(relp + (size_t)p * HID_ + h * D_ + cid * 8);
    }
#pragma unroll
    for (int t = 0; t < 4; t++) {
      int c = (w * 4 + t) * 64 + lane;
      int row = c >> 4;
      int cid = (c & 15) ^ (row & 15);
      vnxt[t] = *(const short8*)(vtbase + (size_t)row * KL_ + cid * 8);
    }
    if (tid < 192) { int p = pb0 + tid; p = p < KL_ ? p : KL_ - 1; eng = ebb[p]; }
    if (tid < 128) cng = cbb[tid];
  }

  for (int kt = 0; kt < ntiles; kt++) {
    const int j0 = kt * WT_;
    const int pbase = pb0 + j0;

    __syncthreads();  // A: prev-iter LDS consumers (PV reads of sk/srel) done
#pragma unroll
    for (int t = 0; t < 4; t++) { int c = (w * 4 + t) * 64 + lane; *(short8*)((char*)sk + c * 16) = krg[t]; }
#pragma unroll
    for (int t = 0; t < 6; t++) { int c = t * 256 + tid; *(short8*)((char*)srel + c * 16) = rrg[t]; }
    if (tid < 192) se[tid] = eng;
    if (tid < 128) sc[tid] = cng;
#pragma unroll
    for (int t = 0; t < 4; t++) vcur[t] = vnxt[t];
    __syncthreads();  // B: staging visible

    // ---- prefetch tile kt+1 into regs (hidden behind this tile's compute) ----
    if (kt + 1 < ntiles) {
      const int j0n = j0 + WT_;
      const int pbn = pbase + WT_;
#pragma unroll
      for (int t = 0; t < 4; t++) {
        int c = (w * 4 + t) * 64 + lane;
        int row = c >> 3;
        int cid = (c & 7) ^ (row & 7);
        krg[t] = *(const short8*)(kbase + (size_t)(j0n + row) * HID_ + cid * 8);
      }
#pragma unroll
      for (int t = 0; t < 6; t++) {
        int c = t * 256 + tid;
        int row = c >> 3;
        int cid = (c & 7) ^ (row & 7);
        int p = pbn + row; p = p < KL_ ? p : KL_ - 1;
        rrg[t] = *(const short8*)(relp + (size_t)p * HID_ + h * D_ + cid * 8);
      }
#pragma unroll
      for (int t = 0; t < 4; t++) {
        int c = (w * 4 + t) * 64 + lane;
        int row = c >> 4;
        int cid = (c & 15) ^ (row & 15);
        vnxt[t] = *(const short8*)(vtbase + (size_t)row * KL_ + j0n + cid * 8);
      }
      if (tid < 192) { int p = pbn + tid; p = p < KL_ ? p : KL_ - 1; eng = ebb[p]; }
      if (tid < 128) cng = cbb[j0n + tid];
    }

    // ---- AD = q . k^T ----
    f32x4 S[8];
#pragma unroll
    for (int nt = 0; nt < 8; nt++) S[nt] = fz;
#pragma unroll
    for (int ks = 0; ks < 2; ks++)
#pragma unroll
      for (int nt = 0; nt < 8; nt++) {
        int r = nt * 16 + l16;
        int cid = (ks * 4 + quad) ^ (r & 7);
        short8 bfv = *(const short8*)((const char*)sk + r * 128 + cid * 16);
        S[nt] = __builtin_amdgcn_mfma_f32_16x16x32_bf16(qf[ks], bfv, S[nt], 0, 0, 0);
      }

    // ---- T band (192 cols), shifted store into sTs (no intra-chunk barriers) ----
#pragma unroll
    for (int ch = 0; ch < 3; ch++) {
      f32x4 T[4];
#pragma unroll
      for (int nt = 0; nt < 4; nt++) T[nt] = fz;
#pragma unroll
      for (int ks = 0; ks < 2; ks++)
#pragma unroll
        for (int nt = 0; nt < 4; nt++) {
          int r = ch * 64 + nt * 16 + l16;
          int cid = (ks * 4 + quad) ^ (r & 7);
          short8 bfv = *(const short8*)((const char*)srel + r * 128 + cid * 16);
          T[nt] = __builtin_amdgcn_mfma_f32_16x16x32_bf16(qf[ks], bfv, T[nt], 0, 0, 0);
        }
#pragma unroll
      for (int nt = 0; nt < 4; nt++)
#pragma unroll
        for (int rg = 0; rg < 4; rg++) {
          int di = w * 16 + quad * 4 + rg;
          int tc = ch * 64 + nt * 16 + l16;
          int jj = tc - 63 + di;                 // shift applied at write time
          float val = T[nt][rg] + se[tc];
          if (jj >= 0 && jj < 128)
            sTs[di * 136 + jj] = __float2bfloat16(val);
        }
    }

    // ---- gather (wave-private rows: no barrier needed) ----
#pragma unroll
    for (int nt = 0; nt < 8; nt++)
#pragma unroll
      for (int rg = 0; rg < 4; rg++) {
        int di = w * 16 + quad * 4 + rg;
        int jj = nt * 16 + l16;
        S[nt][rg] += __bfloat162float(sTs[di * 136 + jj]);
      }

    // ---- logits, causal mask, online softmax ----
    float mnew[4];
#pragma unroll
    for (int rg = 0; rg < 4; rg++) mnew[rg] = mrow[rg];
#pragma unroll
    for (int nt = 0; nt < 8; nt++) {
      int jj = nt * 16 + l16;
      int j = j0 + jj;
      float cbv = sc[jj];
#pragma unroll
      for (int rg = 0; rg < 4; rg++) {
        int i = i0 + w * 16 + quad * 4 + rg;
        float v = (S[nt][rg] + cbv) * (1.0f / 64.0f);
        if (j - i > M_) v = -1e30f;
        S[nt][rg] = v;
        mnew[rg] = fmaxf(mnew[rg], v);
      }
    }
#pragma unroll
    for (int o = 1; o < 16; o <<= 1)
#pragma unroll
      for (int rg = 0; rg < 4; rg++) mnew[rg] = fmaxf(mnew[rg], __shfl_xor(mnew[rg], o, 64));
    float alpha[4];
#pragma unroll
    for (int rg = 0; rg < 4; rg++) {
      alpha[rg] = __expf(mrow[rg] - mnew[rg]);
      mrow[rg] = mnew[rg];
      lrow[rg] *= alpha[rg];
      lmrow[rg] *= alpha[rg];
    }
#pragma unroll
    for (int dt = 0; dt < 4; dt++)
#pragma unroll
      for (int rg = 0; rg < 4; rg++) oacc[dt][rg] *= alpha[rg];

    // P = exp(S-m) * span_mask, kept in S regs until barrier C
#pragma unroll
    for (int nt = 0; nt < 8; nt++) {
      int jj = nt * 16 + l16;
      int j = j0 + jj;
      float mk;
      if (j < M_) mk = 1.f;
      else {
        float t0 = (float)(j - M_) + sv * (float)Q_;
        mk = fminf(fmaxf(t0 * (1.0f / 33.0f), 0.f), 1.f);
      }
#pragma unroll
      for (int rg = 0; rg < 4; rg++) {
        float pv = __expf(S[nt][rg] - mrow[rg]);
        lrow[rg] += pv;
        float pm = pv * mk;
        lmrow[rg] += pm;
        S[nt][rg] = pm;
      }
    }

    __syncthreads();  // C: all waves' AD reads of sk + T reads of srel done

    // write P into sk [64][128]; store V into srel (rel band is dead)
#pragma unroll
    for (int nt = 0; nt < 8; nt++)
#pragma unroll
      for (int rg = 0; rg < 4; rg++) {
        int di = w * 16 + quad * 4 + rg;
        int jj = nt * 16 + l16;
        int cid = (jj >> 3) ^ (di & 15);
        *(__hip_bfloat16*)((char*)sk + di * 256 + cid * 16 + (jj & 7) * 2) = __float2bfloat16(S[nt][rg]);
      }
#pragma unroll
    for (int t = 0; t < 4; t++) { int c = (w * 4 + t) * 64 + lane; *(short8*)((char*)srel + c * 16) = vcur[t]; }

    __syncthreads();  // D: P + V visible

    // PV: oacc[m=i][n=d] += P[i][j] * V[j][d]
#pragma unroll
    for (int ks = 0; ks < 4; ks++) {
      int ar = w * 16 + l16;
      int acid = (ks * 4 + quad) ^ (ar & 15);
      short8 af = *(const short8*)((const char*)sk + ar * 256 + acid * 16);
#pragma unroll
      for (int dt = 0; dt < 4; dt++) {
        int br = dt * 16 + l16;
        int bcid = (ks * 4 + quad) ^ (br & 15);
        short8 bfv = *(const short8*)((const char*)srel + br * 256 + bcid * 16);
        oacc[dt] = __builtin_amdgcn_mfma_f32_16x16x32_bf16(af, bfv, oacc[dt], 0, 0, 0);
      }
    }
  }

#pragma unroll
  for (int o = 1; o < 16; o <<= 1)
#pragma unroll
    for (int rg = 0; rg < 4; rg++) {
      lrow[rg] += __shfl_xor(lrow[rg], o, 64);
      lmrow[rg] += __shfl_xor(lmrow[rg], o, 64);
    }
#pragma unroll
  for (int dt = 0; dt < 4; dt++)
#pragma unroll
    for (int rg = 0; rg < 4; rg++) {
      int i = i0 + w * 16 + quad * 4 + rg;
      float denom = lmrow[rg] + 1e-8f * lrow[rg];
      float ov = oacc[dt][rg] / denom;
      attn_out[((size_t)(b * Q_ + i)) * HID_ + h * D_ + dt * 16 + l16] = __float2bfloat16(ov);
    }
}

// ---------------- launcher ----------------
extern "C" void kernel_launch(void* const* d_in, const int* in_sizes, int n_in,
                              void* d_out, int out_size, void* d_ws, size_t ws_size,
                              hipStream_t stream) {
  const void* query  = d_in[0];
  const void* memory = d_in[1];
  const void* Wq = d_in[2];
  const void* Wk = d_in[3];
  const void* Wv = d_in[4];
  const void* Wo = d_in[5];
  const void* Wr = d_in[6];
  const void* gmem = d_in[7];
  const void* bmem = d_in[8];
  const void* gq = d_in[9];
  const void* bq = d_in[10];
  const void* rwb = d_in[11];
  const void* rrb = d_in[12];
  const void* spanv = d_in[13];

  char* ws = (char*)d_ws;
  size_t off = 0;
  auto alloc = [&](size_t bytes) -> char* {
    char* p = ws + off;
    off += (bytes + 255) & ~(size_t)255;
    return p;
  };
  int* flag = (int*)alloc(256);
  const size_t SZ_W = (size_t)HID_ * HID_ * 2;
  __hip_bfloat16* wqT = (__hip_bfloat16*)alloc(SZ_W);
  __hip_bfloat16* wkT = (__hip_bfloat16*)alloc(SZ_W);
  __hip_bfloat16* wvT = (__hip_bfloat16*)alloc(SZ_W);
  __hip_bfloat16* wrT = (__hip_bfloat16*)alloc(SZ_W);
  __hip_bfloat16* woT = (__hip_bfloat16*)alloc(SZ_W);
  __hip_bfloat16* kvln = (__hip_bfloat16*)alloc((size_t)B_ * KL_ * HID_ * 2);
  __hip_bfloat16* qln  = (__hip_bfloat16*)alloc((size_t)B_ * Q_ * HID_ * 2);
  __hip_bfloat16* pe   = (__hip_bfloat16*)alloc((size_t)KL_ * HID_ * 2);
  __hip_bfloat16* qpb  = (__hip_bfloat16*)alloc((size_t)B_ * Q_ * HID_ * 2);
  __hip_bfloat16* kpb  = (__hip_bfloat16*)alloc((size_t)B_ * KL_ * HID_ * 2);
  __hip_bfloat16* vpb  = (__hip_bfloat16*)alloc((size_t)B_ * KL_ * HID_ * 2);
  __hip_bfloat16* relp = (__hip_bfloat16*)alloc((size_t)KL_ * HID_ * 2);
  __hip_bfloat16* aout = (__hip_bfloat16*)alloc((size_t)B_ * Q_ * HID_ * 2);
  float* cbf = (float*)alloc((size_t)B_ * H_ * KL_ * 4);
  float* ebf = (float*)alloc((size_t)H_ * KL_ * 4);
  __hip_bfloat16* vptb = kvln;  // alias: kvln dead after the k/v projection GEMMs

  dim3 tb(256);
  detect_kernel<<<dim3(1), tb, 0, stream>>>((const unsigned int*)query, flag);

  wt_kernel<<<dim3(16, 16), tb, 0, stream>>>(Wq, wqT, flag);
  wt_kernel<<<dim3(16, 16), tb, 0, stream>>>(Wk, wkT, flag);
  wt_kernel<<<dim3(16, 16), tb, 0, stream>>>(Wv, wvT, flag);
  wt_kernel<<<dim3(16, 16), tb, 0, stream>>>(Wr, wrT, flag);
  wt_kernel<<<dim3(16, 16), tb, 0, stream>>>(Wo, woT, flag);

  ln_kv_kernel<<<dim3(B_ * KL_), tb, 0, stream>>>(memory, query, gmem, bmem, kvln, flag);
  ln_q_kernel<<<dim3(B_ * Q_), tb, 0, stream>>>(query, gq, bq, qln, flag);
  posemb_kernel<<<dim3(KL_), tb, 0, stream>>>(pe);

  gemm_bt128<<<dim3(B_ * Q_ / 128, HID_ / 128), tb, 0, stream>>>(qln, wqT, qpb);
  gemm_bt128<<<dim3(B_ * KL_ / 128, HID_ / 128), tb, 0, stream>>>(kvln, wkT, kpb);
  gemm_bt128<<<dim3(B_ * KL_ / 128, HID_ / 128), tb, 0, stream>>>(kvln, wvT, vpb);
  gemm_bt128<<<dim3(KL_ / 128, HID_ / 128), tb, 0, stream>>>(pe, wrT, relp);

  vpt_kernel<<<dim3(KL_ / 64, B_ * H_), tb, 0, stream>>>(vpb, vptb);
  cbias_kernel<<<dim3(B_ * H_ * KL_ / 256), tb, 0, stream>>>(kpb, rwb, cbf, flag);
  ebias_kernel<<<dim3(H_ * KL_ / 256), tb, 0, stream>>>(relp, rrb, ebf, flag);

  attn_kernel<<<dim3(Q_ / RT_, H_, B_), tb, 0, stream>>>(qpb, kpb, vptb, relp, cbf, ebf, spanv, aout, flag);

  gemm_out<<<dim3(B_ * Q_ / 128, HID_ / 128), tb, 0, stream>>>(aout, woT, d_out, flag);

  (void)in_sizes; (void)n_in; (void)out_size; (void)ws_size;
}

// Round 4
// 1100.048 us; speedup vs baseline: 1.1201x; 1.1029x over previous
//
#include <hip/hip_runtime.h>
#include <hip/hip_bf16.h>
#include <math.h>

#define B_   2
#define Q_   2048
#define M_   2048
#define H_   16
#define D_   64
#define HID_ 1024
#define KL_  4096
#define RT_  64      // q rows per attention block
#define WT_  128     // k cols per attention tile
#define EPAD 256     // e-table tail padding (band reads past KL land here)

typedef short short8 __attribute__((ext_vector_type(8)));
typedef short short4v __attribute__((ext_vector_type(4)));
typedef float f32x4 __attribute__((ext_vector_type(4)));

// read input element i as float, md=1 -> fp32 buffer, md=0 -> bf16 buffer
__device__ __forceinline__ float ldin(const void* p, size_t i, int md) {
  return md ? ((const float*)p)[i] : __bfloat162float(((const __hip_bfloat16*)p)[i]);
}

__device__ __forceinline__ short bfbits(float v) {
  __hip_bfloat16 t = __float2bfloat16(v);
  return *(short*)&t;
}

// ---------------- dtype detector: writes 1 if inputs are fp32, else 0 ----------------
__global__ __launch_bounds__(256) void detect_kernel(const unsigned int* __restrict__ q,
                                                     int* __restrict__ flag) {
  __shared__ int cnt;
  if (threadIdx.x == 0) cnt = 0;
  __syncthreads();
  int ins = 0;
#pragma unroll
  for (int i = 0; i < 4; i++) {
    unsigned int u = q[threadIdx.x * 4 + i];
    int e0 = (int)((u >> 7) & 0xffu);
    int e1 = (int)((u >> 23) & 0xffu);
    if (e0 == 0xff || e0 < 102 || e0 > 140) ins++;
    if (e1 == 0xff || e1 < 102 || e1 > 140) ins++;
  }
  atomicAdd(&cnt, ins);
  __syncthreads();
  if (threadIdx.x == 0) *flag = (cnt > 512) ? 1 : 0;
}

// ---------------- weight transpose: wt[n][k] = src[k][n], 1024x1024 ----------------
__global__ __launch_bounds__(256) void wt_kernel(const void* __restrict__ src,
                                                 __hip_bfloat16* __restrict__ wt,
                                                 const int* __restrict__ mode) {
  const int md = *mode;
  const int r0 = blockIdx.x * 64, c0 = blockIdx.y * 64;
  __shared__ __hip_bfloat16 t[64][65];
  const int tid = threadIdx.x;
  const int col = tid & 63, r4 = tid >> 6;
#pragma unroll
  for (int i = 0; i < 16; i++)
    t[r4 + i * 4][col] = __float2bfloat16(ldin(src, (size_t)(r0 + r4 + i * 4) * HID_ + c0 + col, md));
  __syncthreads();
#pragma unroll
  for (int i = 0; i < 16; i++)
    wt[(size_t)(c0 + r4 + i * 4) * HID_ + r0 + col] = t[col][r4 + i * 4];
}

// ---------------- V transpose: vpt[b][h][d][j] = vp[b*K+j][h*64+d] ----------------
__global__ __launch_bounds__(256) void vpt_kernel(const __hip_bfloat16* __restrict__ vp,
                                                  __hip_bfloat16* __restrict__ vpt) {
  const int jt = blockIdx.x * 64;
  const int bh = blockIdx.y;
  const int b = bh / H_, h = bh % H_;
  __shared__ __hip_bfloat16 t[64][65];
  const int tid = threadIdx.x;
  const int col = tid & 63, r4 = tid >> 6;
#pragma unroll
  for (int i = 0; i < 16; i++) {
    int j = r4 + i * 4;
    t[j][col] = vp[((size_t)b * KL_ + jt + j) * HID_ + h * D_ + col];
  }
  __syncthreads();
#pragma unroll
  for (int i = 0; i < 16; i++) {
    int d = r4 + i * 4;
    vpt[(((size_t)b * H_ + h) * D_ + d) * KL_ + jt + col] = t[col][d];
  }
}

// ---------------- LayerNorm over concat(memory, query) rows ----------------
__global__ __launch_bounds__(256) void ln_kv_kernel(
    const void* __restrict__ mem, const void* __restrict__ qry,
    const void* __restrict__ gamma, const void* __restrict__ beta,
    __hip_bfloat16* __restrict__ out, const int* __restrict__ mode) {
  const int md = *mode;
  const int row = blockIdx.x;  // 0..B*KL-1
  const int b = row / KL_, j = row % KL_;
  const void* src;
  size_t base;
  if (j < M_) { src = mem; base = ((size_t)b * M_ + j) * HID_; }
  else        { src = qry; base = ((size_t)b * Q_ + (j - M_)) * HID_; }
  const int tid = threadIdx.x;
  float x[4];
  float s = 0.f, ss = 0.f;
#pragma unroll
  for (int i = 0; i < 4; i++) {
    x[i] = ldin(src, base + i * 256 + tid, md);
    s += x[i]; ss += x[i] * x[i];
  }
#pragma unroll
  for (int o = 32; o > 0; o >>= 1) { s += __shfl_down(s, o); ss += __shfl_down(ss, o); }
  __shared__ float red[8];
  if ((tid & 63) == 0) { red[(tid >> 6) * 2] = s; red[(tid >> 6) * 2 + 1] = ss; }
  __syncthreads();
  float ts = 0.f, tss = 0.f;
#pragma unroll
  for (int i = 0; i < 4; i++) { ts += red[i * 2]; tss += red[i * 2 + 1]; }
  const float mu = ts * (1.f / 1024.f);
  const float var = tss * (1.f / 1024.f) - mu * mu;
  const float rs = rsqrtf(var + 1e-3f);
  __hip_bfloat16* dst = out + (size_t)row * HID_;
#pragma unroll
  for (int i = 0; i < 4; i++) {
    int c = i * 256 + tid;
    dst[c] = __float2bfloat16((x[i] - mu) * rs * ldin(gamma, c, md) + ldin(beta, c, md));
  }
}

__global__ __launch_bounds__(256) void ln_q_kernel(
    const void* __restrict__ qry,
    const void* __restrict__ gamma, const void* __restrict__ beta,
    __hip_bfloat16* __restrict__ out, const int* __restrict__ mode) {
  const int md = *mode;
  const int row = blockIdx.x;  // 0..B*Q-1
  const size_t base = (size_t)row * HID_;
  const int tid = threadIdx.x;
  float x[4];
  float s = 0.f, ss = 0.f;
#pragma unroll
  for (int i = 0; i < 4; i++) {
    x[i] = ldin(qry, base + i * 256 + tid, md);
    s += x[i]; ss += x[i] * x[i];
  }
#pragma unroll
  for (int o = 32; o > 0; o >>= 1) { s += __shfl_down(s, o); ss += __shfl_down(ss, o); }
  __shared__ float red[8];
  if ((tid & 63) == 0) { red[(tid >> 6) * 2] = s; red[(tid >> 6) * 2 + 1] = ss; }
  __syncthreads();
  float ts = 0.f, tss = 0.f;
#pragma unroll
  for (int i = 0; i < 4; i++) { ts += red[i * 2]; tss += red[i * 2 + 1]; }
  const float mu = ts * (1.f / 1024.f);
  const float var = tss * (1.f / 1024.f) - mu * mu;
  const float rs = rsqrtf(var + 1e-3f);
  __hip_bfloat16* dst = out + (size_t)row * HID_;
#pragma unroll
  for (int i = 0; i < 4; i++) {
    int c = i * 256 + tid;
    dst[c] = __float2bfloat16((x[i] - mu) * rs * ldin(gamma, c, md) + ldin(beta, c, md));
  }
}

// ---------------- sinusoidal position embedding, positions K-1..0 ----------------
__global__ __launch_bounds__(256) void posemb_kernel(__hip_bfloat16* __restrict__ pe) {
  const int p = blockIdx.x;
  const float pos = (float)(KL_ - 1 - p);
  const int tid = threadIdx.x;
#pragma unroll
  for (int i = 0; i < 4; i++) {
    int c = tid * 4 + i;
    int f = (c < 512) ? c : c - 512;
    float invf = powf(10000.0f, -(float)f * (1.0f / 512.0f));
    float a = pos * invf;
    float v = (c < 512) ? sinf(a) : cosf(a);
    pe[(size_t)p * HID_ + c] = __float2bfloat16(v);
  }
}

// ---------------- GEMM core: C = A @ BT^T (both bf16, K=1024), 128x128 tile ----------------
template <int WRITE_MODE_SWITCH>
__device__ __forceinline__ void gemm_body(const __hip_bfloat16* __restrict__ A,
                                          const __hip_bfloat16* __restrict__ BT,
                                          void* __restrict__ C, int md) {
  __shared__ __attribute__((aligned(16))) __hip_bfloat16 sA[128 * 32];
  __shared__ __attribute__((aligned(16))) __hip_bfloat16 sB[128 * 32];
  const int tid = threadIdx.x;
  const int lane = tid & 63;
  const int w = tid >> 6;
  const int quad = lane >> 4, l16 = lane & 15;
  const int m0 = blockIdx.x * 128;
  const int n0 = blockIdx.y * 128;
  const int wm = (w >> 1) * 64, wn = (w & 1) * 64;
  const f32x4 fz = {0.f, 0.f, 0.f, 0.f};

  f32x4 acc[4][4];
#pragma unroll
  for (int i = 0; i < 4; i++)
#pragma unroll
    for (int j = 0; j < 4; j++) acc[i][j] = fz;

  for (int kk = 0; kk < HID_ / 32; kk++) {
    const int k0 = kk * 32;
    short8 ar[2], br[2];
#pragma unroll
    for (int t = 0; t < 2; t++) {
      int c = (w * 2 + t) * 64 + lane;
      int row = c >> 2;
      int cid = (c & 3) ^ (row & 3);
      ar[t] = *(const short8*)(A + (size_t)(m0 + row) * HID_ + k0 + cid * 8);
      br[t] = *(const short8*)(BT + (size_t)(n0 + row) * HID_ + k0 + cid * 8);
    }
    __syncthreads();
#pragma unroll
    for (int t = 0; t < 2; t++) {
      int c = (w * 2 + t) * 64 + lane;
      *(short8*)((char*)sA + c * 16) = ar[t];
      *(short8*)((char*)sB + c * 16) = br[t];
    }
    __syncthreads();
    short8 af[4], bf[4];
#pragma unroll
    for (int mt = 0; mt < 4; mt++) {
      int r = wm + mt * 16 + l16;
      af[mt] = *(const short8*)((const char*)sA + r * 64 + ((quad ^ (r & 3)) * 16));
    }
#pragma unroll
    for (int nt = 0; nt < 4; nt++) {
      int r = wn + nt * 16 + l16;
      bf[nt] = *(const short8*)((const char*)sB + r * 64 + ((quad ^ (r & 3)) * 16));
    }
#pragma unroll
    for (int mt = 0; mt < 4; mt++)
#pragma unroll
      for (int nt = 0; nt < 4; nt++)
        acc[mt][nt] = __builtin_amdgcn_mfma_f32_16x16x32_bf16(af[mt], bf[nt], acc[mt][nt], 0, 0, 0);
  }
#pragma unroll
  for (int mt = 0; mt < 4; mt++)
#pragma unroll
    for (int nt = 0; nt < 4; nt++)
#pragma unroll
      for (int rg = 0; rg < 4; rg++) {
        int r = m0 + wm + mt * 16 + quad * 4 + rg;
        int cc = n0 + wn + nt * 16 + l16;
        size_t idx = (size_t)r * HID_ + cc;
        if (WRITE_MODE_SWITCH && md) ((float*)C)[idx] = acc[mt][nt][rg];
        else ((__hip_bfloat16*)C)[idx] = __float2bfloat16(acc[mt][nt][rg]);
      }
}

__global__ __launch_bounds__(256) void gemm_bt128(const __hip_bfloat16* __restrict__ A,
                                                  const __hip_bfloat16* __restrict__ BT,
                                                  __hip_bfloat16* __restrict__ C) {
  gemm_body<0>(A, BT, (void*)C, 0);
}

__global__ __launch_bounds__(256) void gemm_out(const __hip_bfloat16* __restrict__ A,
                                                const __hip_bfloat16* __restrict__ BT,
                                                void* __restrict__ C,
                                                const int* __restrict__ mode) {
  gemm_body<1>(A, BT, C, *mode);
}

// ---------------- bias dots: c[b][h][j] = rwb_h . k_j ; e[h][p] = rrb_h . rel_p (padded) ----------------
__global__ __launch_bounds__(256) void cbias_kernel(const __hip_bfloat16* __restrict__ kp,
                                                    const void* __restrict__ rwb,
                                                    float* __restrict__ cb,
                                                    const int* __restrict__ mode) {
  const int md = *mode;
  const int idx = blockIdx.x * 256 + threadIdx.x;  // B*H*KL
  const int j = idx % KL_;
  const int h = (idx / KL_) % H_;
  const int b = idx / (KL_ * H_);
  const __hip_bfloat16* kr = kp + ((size_t)b * KL_ + j) * HID_ + h * D_;
  float s = 0.f;
#pragma unroll 8
  for (int d = 0; d < D_; d++) s += __bfloat162float(kr[d]) * ldin(rwb, h * D_ + d, md);
  cb[idx] = s;
}

__global__ __launch_bounds__(256) void ebias_kernel(const __hip_bfloat16* __restrict__ relp,
                                                    const void* __restrict__ rrb,
                                                    float* __restrict__ eb,
                                                    const int* __restrict__ mode) {
  const int md = *mode;
  const int idx = blockIdx.x * 256 + threadIdx.x;  // H*(KL+EPAD)
  const int p = idx % (KL_ + EPAD);
  const int h = idx / (KL_ + EPAD);
  const int pc = p < KL_ ? p : KL_ - 1;            // pad rows: finite junk (masked downstream)
  const __hip_bfloat16* rr = relp + (size_t)pc * HID_ + h * D_;
  float s = 0.f;
#pragma unroll 8
  for (int d = 0; d < D_; d++) s += __bfloat162float(rr[d]) * ldin(rrb, h * D_ + d, md);
  eb[idx] = s;
}

// ---------------- fused relative attention: transposed-S, barrier-free ----------------
// grid 1024 flat (XCD-remapped), block 256 (4 waves, each owns a 16-row q strip).
// All MFMA operands read straight from global (L2-resident via XCD swizzle); LDS holds
// only the wave-private T-band / P round-trips (one 64x200-half buffer, disjoint lifetimes).
__global__ __launch_bounds__(256, 3) void attn_kernel(
    const __hip_bfloat16* __restrict__ qp, const __hip_bfloat16* __restrict__ kp,
    const __hip_bfloat16* __restrict__ vpt, const __hip_bfloat16* __restrict__ relp,
    const float* __restrict__ cb, const float* __restrict__ eb,
    const void* __restrict__ spanv, __hip_bfloat16* __restrict__ attn_out,
    const int* __restrict__ mode) {
  const int md = *mode;
  // XCD-locality remap: the 32 i0-blocks of one (b,h) share an XCD (bid%8 heuristic)
  const int bid = blockIdx.x;
  const int bh = (bid & 7) + 8 * (bid >> 8);   // bid>>3 >>5
  const int i0 = (((bid >> 3) & 31)) * RT_;
  const int b = bh >> 4, h = bh & 15;

  const int tid = threadIdx.x;
  const int lane = tid & 63;
  const int w = tid >> 6;
  const int quad = lane >> 4, l16 = lane & 15;
  const int di = w * 16 + l16;        // this thread's softmax row (block-local)
  const int iRow = i0 + di;           // absolute q row for softmax state
  const f32x4 fz = {0.f, 0.f, 0.f, 0.f};

  __shared__ __attribute__((aligned(16))) short sb[64 * 200];  // 25.6 KB, wave-private rows

  // q fragments (B-operand): lane l16 = q row di, k = ks*32+quad*8
  const __hip_bfloat16* qrow = qp + ((size_t)(b * Q_ + iRow)) * HID_ + h * D_;
  short8 qf[2];
#pragma unroll
  for (int ks = 0; ks < 2; ks++) qf[ks] = *(const short8*)(qrow + ks * 32 + quad * 8);

  float mrow = -3e38f, lrow = 0.f, lmrow = 0.f;
  f32x4 oacc[4];
#pragma unroll
  for (int dt = 0; dt < 4; dt++) oacc[dt] = fz;

  const __hip_bfloat16* kbase = kp + (size_t)b * KL_ * HID_ + h * D_;
  const __hip_bfloat16* vtb = vpt + ((size_t)(b * H_ + h)) * D_ * KL_;
  const float* cbb = cb + (size_t)(b * H_ + h) * KL_;
  const float* ebb = eb + (size_t)h * (KL_ + EPAD);
  const float sv = ldin(spanv, h, md);
  const int pb0 = Q_ - RT_ - i0;
  const int wof = (3 - w) * 16;       // this wave's T-band p-offset
  const int ntiles = ((M_ + i0 + RT_ - 1) >> 7) + 1;

  for (int kt = 0; kt < ntiles; kt++) {
    const int j0 = kt * WT_;
    const int pbase = pb0 + j0;

    // ---- S^T[j][i] = K . Q^T : A = K rows (m=j), B = q (n=i) ----
    f32x4 S[8];
#pragma unroll
    for (int mt = 0; mt < 8; mt++) S[mt] = fz;
#pragma unroll
    for (int mt = 0; mt < 8; mt++) {
      const __hip_bfloat16* kr = kbase + (size_t)(j0 + mt * 16 + l16) * HID_;
#pragma unroll
      for (int ks = 0; ks < 2; ks++) {
        short8 af = *(const short8*)(kr + ks * 32 + quad * 8);
        S[mt] = __builtin_amdgcn_mfma_f32_16x16x32_bf16(af, qf[ks], S[mt], 0, 0, 0);
      }
    }

    // ---- T band (wave's 144-col p-window), unshifted store [di][po], +e ----
#pragma unroll
    for (int mt = 0; mt < 9; mt++) {
      f32x4 T = fz;
      int prow = pbase + wof + mt * 16 + l16;
      prow = prow < KL_ ? prow : KL_ - 1;   // clamped rows feed only masked cols
      const __hip_bfloat16* rr = relp + (size_t)prow * HID_ + h * D_;
#pragma unroll
      for (int ks = 0; ks < 2; ks++) {
        short8 af = *(const short8*)(rr + ks * 32 + quad * 8);
        T = __builtin_amdgcn_mfma_f32_16x16x32_bf16(af, qf[ks], T, 0, 0, 0);
      }
      const int po0 = wof + mt * 16 + quad * 4;
      f32x4 e4 = *(const f32x4*)(ebb + pbase + po0);   // padded table: never OOB
      short4v pk;
#pragma unroll
      for (int rg = 0; rg < 4; rg++) pk[rg] = bfbits(T[rg] + e4[rg]);
      *(short4v*)(&sb[di * 200 + po0]) = pk;
    }

    // ---- gather with per-row shift (wave-private rows, in-order DS) ----
#pragma unroll
    for (int mt = 0; mt < 8; mt++)
#pragma unroll
      for (int rg = 0; rg < 4; rg++) {
        int tc = 63 - di + mt * 16 + quad * 4 + rg;
        S[mt][rg] += __bfloat162float(*(const __hip_bfloat16*)&sb[di * 200 + tc]);
      }

    // ---- logits, causal mask, online softmax (state per thread = one row) ----
    float mnew = mrow;
#pragma unroll
    for (int mt = 0; mt < 8; mt++) {
      f32x4 cb4 = *(const f32x4*)(cbb + j0 + mt * 16 + quad * 4);
#pragma unroll
      for (int rg = 0; rg < 4; rg++) {
        int j = j0 + mt * 16 + quad * 4 + rg;
        float v = (S[mt][rg] + cb4[rg]) * (1.0f / 64.0f);
        if (j - iRow > M_) v = -1e30f;
        S[mt][rg] = v;
        mnew = fmaxf(mnew, v);
      }
    }
    mnew = fmaxf(mnew, __shfl_xor(mnew, 16));
    mnew = fmaxf(mnew, __shfl_xor(mnew, 32));
    const float alpha = __expf(mrow - mnew);
    mrow = mnew;
    lrow *= alpha; lmrow *= alpha;
    float aR[4];
#pragma unroll
    for (int rg = 0; rg < 4; rg++) aR[rg] = __shfl(alpha, quad * 4 + rg);
#pragma unroll
    for (int dt = 0; dt < 4; dt++)
#pragma unroll
      for (int rg = 0; rg < 4; rg++) oacc[dt][rg] *= aR[rg];

    // ---- P = exp(S-m)*span, packed b64 into sb rows [di][j 0..128) ----
#pragma unroll
    for (int mt = 0; mt < 8; mt++) {
      short4v pk;
#pragma unroll
      for (int rg = 0; rg < 4; rg++) {
        int j = j0 + mt * 16 + quad * 4 + rg;
        float mk;
        if (j < M_) mk = 1.f;
        else {
          float t0 = (float)(j - M_) + sv * (float)Q_;
          mk = fminf(fmaxf(t0 * (1.0f / 33.0f), 0.f), 1.f);
        }
        float pv = __expf(S[mt][rg] - mrow);
        lrow += pv;
        float pm = pv * mk;
        lmrow += pm;
        pk[rg] = bfbits(pm);
      }
      *(short4v*)(&sb[di * 200 + mt * 16 + quad * 4]) = pk;
    }

    // ---- PV: A = P (own rows, LDS b128), B = V^T rows (global) ----
#pragma unroll
    for (int ks = 0; ks < 4; ks++) {
      short8 af = *(const short8*)((const char*)sb + di * 400 + ks * 64 + quad * 16);
#pragma unroll
      for (int dt = 0; dt < 4; dt++) {
        short8 bfv = *(const short8*)(vtb + (size_t)(dt * 16 + l16) * KL_ + j0 + ks * 32 + quad * 8);
        oacc[dt] = __builtin_amdgcn_mfma_f32_16x16x32_bf16(af, bfv, oacc[dt], 0, 0, 0);
      }
    }
  }

  // ---- epilogue: cross-quad reduce, per-row denominators via shfl ----
  lrow += __shfl_xor(lrow, 16);  lrow += __shfl_xor(lrow, 32);
  lmrow += __shfl_xor(lmrow, 16); lmrow += __shfl_xor(lmrow, 32);
  float lr4[4], lm4[4];
#pragma unroll
  for (int rg = 0; rg < 4; rg++) {
    lr4[rg] = __shfl(lrow, quad * 4 + rg);
    lm4[rg] = __shfl(lmrow, quad * 4 + rg);
  }
#pragma unroll
  for (int dt = 0; dt < 4; dt++)
#pragma unroll
    for (int rg = 0; rg < 4; rg++) {
      int i = i0 + w * 16 + quad * 4 + rg;
      float denom = lm4[rg] + 1e-8f * lr4[rg];
      float ov = oacc[dt][rg] / denom;
      attn_out[((size_t)(b * Q_ + i)) * HID_ + h * D_ + dt * 16 + l16] = __float2bfloat16(ov);
    }
}

// ---------------- launcher ----------------
extern "C" void kernel_launch(void* const* d_in, const int* in_sizes, int n_in,
                              void* d_out, int out_size, void* d_ws, size_t ws_size,
                              hipStream_t stream) {
  const void* query  = d_in[0];
  const void* memory = d_in[1];
  const void* Wq = d_in[2];
  const void* Wk = d_in[3];
  const void* Wv = d_in[4];
  const void* Wo = d_in[5];
  const void* Wr = d_in[6];
  const void* gmem = d_in[7];
  const void* bmem = d_in[8];
  const void* gq = d_in[9];
  const void* bq = d_in[10];
  const void* rwb = d_in[11];
  const void* rrb = d_in[12];
  const void* spanv = d_in[13];

  char* ws = (char*)d_ws;
  size_t off = 0;
  auto alloc = [&](size_t bytes) -> char* {
    char* p = ws + off;
    off += (bytes + 255) & ~(size_t)255;
    return p;
  };
  int* flag = (int*)alloc(256);
  const size_t SZ_W = (size_t)HID_ * HID_ * 2;
  __hip_bfloat16* wqT = (__hip_bfloat16*)alloc(SZ_W);
  __hip_bfloat16* wkT = (__hip_bfloat16*)alloc(SZ_W);
  __hip_bfloat16* wvT = (__hip_bfloat16*)alloc(SZ_W);
  __hip_bfloat16* wrT = (__hip_bfloat16*)alloc(SZ_W);
  __hip_bfloat16* woT = (__hip_bfloat16*)alloc(SZ_W);
  __hip_bfloat16* kvln = (__hip_bfloat16*)alloc((size_t)B_ * KL_ * HID_ * 2);
  __hip_bfloat16* qln  = (__hip_bfloat16*)alloc((size_t)B_ * Q_ * HID_ * 2);
  __hip_bfloat16* pe   = (__hip_bfloat16*)alloc((size_t)KL_ * HID_ * 2);
  __hip_bfloat16* qpb  = (__hip_bfloat16*)alloc((size_t)B_ * Q_ * HID_ * 2);
  __hip_bfloat16* kpb  = (__hip_bfloat16*)alloc((size_t)B_ * KL_ * HID_ * 2);
  __hip_bfloat16* vpb  = (__hip_bfloat16*)alloc((size_t)B_ * KL_ * HID_ * 2);
  __hip_bfloat16* relp = (__hip_bfloat16*)alloc((size_t)KL_ * HID_ * 2);
  __hip_bfloat16* aout = (__hip_bfloat16*)alloc((size_t)B_ * Q_ * HID_ * 2);
  float* cbf = (float*)alloc((size_t)B_ * H_ * KL_ * 4);
  float* ebf = (float*)alloc((size_t)H_ * (KL_ + EPAD) * 4);
  __hip_bfloat16* vptb = kvln;  // alias: kvln dead after the k/v projection GEMMs

  dim3 tb(256);
  detect_kernel<<<dim3(1), tb, 0, stream>>>((const unsigned int*)query, flag);

  wt_kernel<<<dim3(16, 16), tb, 0, stream>>>(Wq, wqT, flag);
  wt_kernel<<<dim3(16, 16), tb, 0, stream>>>(Wk, wkT, flag);
  wt_kernel<<<dim3(16, 16), tb, 0, stream>>>(Wv, wvT, flag);
  wt_kernel<<<dim3(16, 16), tb, 0, stream>>>(Wr, wrT, flag);
  wt_kernel<<<dim3(16, 16), tb, 0, stream>>>(Wo, woT, flag);

  ln_kv_kernel<<<dim3(B_ * KL_), tb, 0, stream>>>(memory, query, gmem, bmem, kvln, flag);
  ln_q_kernel<<<dim3(B_ * Q_), tb, 0, stream>>>(query, gq, bq, qln, flag);
  posemb_kernel<<<dim3(KL_), tb, 0, stream>>>(pe);

  gemm_bt128<<<dim3(B_ * Q_ / 128, HID_ / 128), tb, 0, stream>>>(qln, wqT, qpb);
  gemm_bt128<<<dim3(B_ * KL_ / 128, HID_ / 128), tb, 0, stream>>>(kvln, wkT, kpb);
  gemm_bt128<<<dim3(B_ * KL_ / 128, HID_ / 128), tb, 0, stream>>>(kvln, wvT, vpb);
  gemm_bt128<<<dim3(KL_ / 128, HID_ / 128), tb, 0, stream>>>(pe, wrT, relp);

  vpt_kernel<<<dim3(KL_ / 64, B_ * H_), tb, 0, stream>>>(vpb, vptb);
  cbias_kernel<<<dim3(B_ * H_ * KL_ / 256), tb, 0, stream>>>(kpb, rwb, cbf, flag);
  ebias_kernel<<<dim3(H_ * (KL_ + EPAD) / 256), tb, 0, stream>>>(relp, rrb, ebf, flag);

  attn_kernel<<<dim3((Q_ / RT_) * H_ * B_), tb, 0, stream>>>(qpb, kpb, vptb, relp, cbf, ebf, spanv, aout, flag);

  gemm_out<<<dim3(B_ * Q_ / 128, HID_ / 128), tb, 0, stream>>>(aout, woT, d_out, flag);

  (void)in_sizes; (void)n_in; (void)out_size; (void)ws_size;
}

// Round 5
// 656.907 us; speedup vs baseline: 1.8757x; 1.6746x over previous
//
#include <hip/hip_runtime.h>
#include <hip/hip_bf16.h>
#include <math.h>

#define B_   2
#define Q_   2048
#define M_   2048
#define H_   16
#define D_   64
#define HID_ 1024
#define KL_  4096
#define RT_  64      // q rows per attention block
#define WT_  128     // k cols per attention tile
#define EPAD 256     // e-table tail padding (band reads past KL land here)

typedef short short8 __attribute__((ext_vector_type(8)));
typedef short short4v __attribute__((ext_vector_type(4)));
typedef float f32x4 __attribute__((ext_vector_type(4)));

__device__ __forceinline__ void async_copy16(const void* g, void* l) {
  __builtin_amdgcn_global_load_lds((const __attribute__((address_space(1))) unsigned int*)g,
                                   (__attribute__((address_space(3))) unsigned int*)l,
                                   16, 0, 0);
}

// read input element i as float, md=1 -> fp32 buffer, md=0 -> bf16 buffer
__device__ __forceinline__ float ldin(const void* p, size_t i, int md) {
  return md ? ((const float*)p)[i] : __bfloat162float(((const __hip_bfloat16*)p)[i]);
}

__device__ __forceinline__ short bfbits(float v) {
  __hip_bfloat16 t = __float2bfloat16(v);
  return *(short*)&t;
}

// ---------------- dtype detector: writes 1 if inputs are fp32, else 0 ----------------
__global__ __launch_bounds__(256) void detect_kernel(const unsigned int* __restrict__ q,
                                                     int* __restrict__ flag) {
  __shared__ int cnt;
  if (threadIdx.x == 0) cnt = 0;
  __syncthreads();
  int ins = 0;
#pragma unroll
  for (int i = 0; i < 4; i++) {
    unsigned int u = q[threadIdx.x * 4 + i];
    int e0 = (int)((u >> 7) & 0xffu);
    int e1 = (int)((u >> 23) & 0xffu);
    if (e0 == 0xff || e0 < 102 || e0 > 140) ins++;
    if (e1 == 0xff || e1 < 102 || e1 > 140) ins++;
  }
  atomicAdd(&cnt, ins);
  __syncthreads();
  if (threadIdx.x == 0) *flag = (cnt > 512) ? 1 : 0;
}

// ---------------- weight transpose: wt[n][k] = src[k][n], 1024x1024 ----------------
__global__ __launch_bounds__(256) void wt_kernel(const void* __restrict__ src,
                                                 __hip_bfloat16* __restrict__ wt,
                                                 const int* __restrict__ mode) {
  const int md = *mode;
  const int r0 = blockIdx.x * 64, c0 = blockIdx.y * 64;
  __shared__ __hip_bfloat16 t[64][65];
  const int tid = threadIdx.x;
  const int col = tid & 63, r4 = tid >> 6;
#pragma unroll
  for (int i = 0; i < 16; i++)
    t[r4 + i * 4][col] = __float2bfloat16(ldin(src, (size_t)(r0 + r4 + i * 4) * HID_ + c0 + col, md));
  __syncthreads();
#pragma unroll
  for (int i = 0; i < 16; i++)
    wt[(size_t)(c0 + r4 + i * 4) * HID_ + r0 + col] = t[col][r4 + i * 4];
}

// ---------------- V transpose: vpt[b][h][d][j] = vp[b*K+j][h*64+d] ----------------
__global__ __launch_bounds__(256) void vpt_kernel(const __hip_bfloat16* __restrict__ vp,
                                                  __hip_bfloat16* __restrict__ vpt) {
  const int jt = blockIdx.x * 64;
  const int bh = blockIdx.y;
  const int b = bh / H_, h = bh % H_;
  __shared__ __hip_bfloat16 t[64][65];
  const int tid = threadIdx.x;
  const int col = tid & 63, r4 = tid >> 6;
#pragma unroll
  for (int i = 0; i < 16; i++) {
    int j = r4 + i * 4;
    t[j][col] = vp[((size_t)b * KL_ + jt + j) * HID_ + h * D_ + col];
  }
  __syncthreads();
#pragma unroll
  for (int i = 0; i < 16; i++) {
    int d = r4 + i * 4;
    vpt[(((size_t)b * H_ + h) * D_ + d) * KL_ + jt + col] = t[col][d];
  }
}

// ---------------- LayerNorm over concat(memory, query) rows ----------------
__global__ __launch_bounds__(256) void ln_kv_kernel(
    const void* __restrict__ mem, const void* __restrict__ qry,
    const void* __restrict__ gamma, const void* __restrict__ beta,
    __hip_bfloat16* __restrict__ out, const int* __restrict__ mode) {
  const int md = *mode;
  const int row = blockIdx.x;  // 0..B*KL-1
  const int b = row / KL_, j = row % KL_;
  const void* src;
  size_t base;
  if (j < M_) { src = mem; base = ((size_t)b * M_ + j) * HID_; }
  else        { src = qry; base = ((size_t)b * Q_ + (j - M_)) * HID_; }
  const int tid = threadIdx.x;
  float x[4];
  float s = 0.f, ss = 0.f;
#pragma unroll
  for (int i = 0; i < 4; i++) {
    x[i] = ldin(src, base + i * 256 + tid, md);
    s += x[i]; ss += x[i] * x[i];
  }
#pragma unroll
  for (int o = 32; o > 0; o >>= 1) { s += __shfl_down(s, o); ss += __shfl_down(ss, o); }
  __shared__ float red[8];
  if ((tid & 63) == 0) { red[(tid >> 6) * 2] = s; red[(tid >> 6) * 2 + 1] = ss; }
  __syncthreads();
  float ts = 0.f, tss = 0.f;
#pragma unroll
  for (int i = 0; i < 4; i++) { ts += red[i * 2]; tss += red[i * 2 + 1]; }
  const float mu = ts * (1.f / 1024.f);
  const float var = tss * (1.f / 1024.f) - mu * mu;
  const float rs = rsqrtf(var + 1e-3f);
  __hip_bfloat16* dst = out + (size_t)row * HID_;
#pragma unroll
  for (int i = 0; i < 4; i++) {
    int c = i * 256 + tid;
    dst[c] = __float2bfloat16((x[i] - mu) * rs * ldin(gamma, c, md) + ldin(beta, c, md));
  }
}

__global__ __launch_bounds__(256) void ln_q_kernel(
    const void* __restrict__ qry,
    const void* __restrict__ gamma, const void* __restrict__ beta,
    __hip_bfloat16* __restrict__ out, const int* __restrict__ mode) {
  const int md = *mode;
  const int row = blockIdx.x;  // 0..B*Q-1
  const size_t base = (size_t)row * HID_;
  const int tid = threadIdx.x;
  float x[4];
  float s = 0.f, ss = 0.f;
#pragma unroll
  for (int i = 0; i < 4; i++) {
    x[i] = ldin(qry, base + i * 256 + tid, md);
    s += x[i]; ss += x[i] * x[i];
  }
#pragma unroll
  for (int o = 32; o > 0; o >>= 1) { s += __shfl_down(s, o); ss += __shfl_down(ss, o); }
  __shared__ float red[8];
  if ((tid & 63) == 0) { red[(tid >> 6) * 2] = s; red[(tid >> 6) * 2 + 1] = ss; }
  __syncthreads();
  float ts = 0.f, tss = 0.f;
#pragma unroll
  for (int i = 0; i < 4; i++) { ts += red[i * 2]; tss += red[i * 2 + 1]; }
  const float mu = ts * (1.f / 1024.f);
  const float var = tss * (1.f / 1024.f) - mu * mu;
  const float rs = rsqrtf(var + 1e-3f);
  __hip_bfloat16* dst = out + (size_t)row * HID_;
#pragma unroll
  for (int i = 0; i < 4; i++) {
    int c = i * 256 + tid;
    dst[c] = __float2bfloat16((x[i] - mu) * rs * ldin(gamma, c, md) + ldin(beta, c, md));
  }
}

// ---------------- sinusoidal position embedding, positions K-1..0 ----------------
__global__ __launch_bounds__(256) void posemb_kernel(__hip_bfloat16* __restrict__ pe) {
  const int p = blockIdx.x;
  const float pos = (float)(KL_ - 1 - p);
  const int tid = threadIdx.x;
#pragma unroll
  for (int i = 0; i < 4; i++) {
    int c = tid * 4 + i;
    int f = (c < 512) ? c : c - 512;
    // 10000^(-f/512) = 2^(-f*log2(1e4)/512)
    float invf = exp2f(-(float)f * (13.287712379549449f / 512.0f));
    float a = pos * invf;
    float v = (c < 512) ? __sinf(a) : __cosf(a);
    pe[(size_t)p * HID_ + c] = __float2bfloat16(v);
  }
}

// ---------------- GEMM core: C = A @ BT^T (both bf16, K=1024), 128x128 tile ----------------
template <int WRITE_MODE_SWITCH>
__device__ __forceinline__ void gemm_body(const __hip_bfloat16* __restrict__ A,
                                          const __hip_bfloat16* __restrict__ BT,
                                          void* __restrict__ C, int md) {
  __shared__ __attribute__((aligned(16))) __hip_bfloat16 sA[128 * 32];
  __shared__ __attribute__((aligned(16))) __hip_bfloat16 sB[128 * 32];
  const int tid = threadIdx.x;
  const int lane = tid & 63;
  const int w = tid >> 6;
  const int quad = lane >> 4, l16 = lane & 15;
  const int m0 = blockIdx.x * 128;
  const int n0 = blockIdx.y * 128;
  const int wm = (w >> 1) * 64, wn = (w & 1) * 64;
  const f32x4 fz = {0.f, 0.f, 0.f, 0.f};

  f32x4 acc[4][4];
#pragma unroll
  for (int i = 0; i < 4; i++)
#pragma unroll
    for (int j = 0; j < 4; j++) acc[i][j] = fz;

  for (int kk = 0; kk < HID_ / 32; kk++) {
    const int k0 = kk * 32;
    __syncthreads();
#pragma unroll
    for (int t = 0; t < 2; t++) {
      int c = (w * 2 + t) * 64 + lane;
      int row = c >> 2;
      int cid = (c & 3) ^ (row & 3);
      async_copy16(A + (size_t)(m0 + row) * HID_ + k0 + cid * 8, (char*)sA + c * 16);
      async_copy16(BT + (size_t)(n0 + row) * HID_ + k0 + cid * 8, (char*)sB + c * 16);
    }
    __syncthreads();
    short8 af[4], bf[4];
#pragma unroll
    for (int mt = 0; mt < 4; mt++) {
      int r = wm + mt * 16 + l16;
      af[mt] = *(const short8*)((const char*)sA + r * 64 + ((quad ^ (r & 3)) * 16));
    }
#pragma unroll
    for (int nt = 0; nt < 4; nt++) {
      int r = wn + nt * 16 + l16;
      bf[nt] = *(const short8*)((const char*)sB + r * 64 + ((quad ^ (r & 3)) * 16));
    }
#pragma unroll
    for (int mt = 0; mt < 4; mt++)
#pragma unroll
      for (int nt = 0; nt < 4; nt++)
        acc[mt][nt] = __builtin_amdgcn_mfma_f32_16x16x32_bf16(af[mt], bf[nt], acc[mt][nt], 0, 0, 0);
  }
#pragma unroll
  for (int mt = 0; mt < 4; mt++)
#pragma unroll
    for (int nt = 0; nt < 4; nt++)
#pragma unroll
      for (int rg = 0; rg < 4; rg++) {
        int r = m0 + wm + mt * 16 + quad * 4 + rg;
        int cc = n0 + wn + nt * 16 + l16;
        size_t idx = (size_t)r * HID_ + cc;
        if (WRITE_MODE_SWITCH && md) ((float*)C)[idx] = acc[mt][nt][rg];
        else ((__hip_bfloat16*)C)[idx] = __float2bfloat16(acc[mt][nt][rg]);
      }
}

__global__ __launch_bounds__(256) void gemm_bt128(const __hip_bfloat16* __restrict__ A,
                                                  const __hip_bfloat16* __restrict__ BT,
                                                  __hip_bfloat16* __restrict__ C) {
  gemm_body<0>(A, BT, (void*)C, 0);
}

__global__ __launch_bounds__(256) void gemm_out(const __hip_bfloat16* __restrict__ A,
                                                const __hip_bfloat16* __restrict__ BT,
                                                void* __restrict__ C,
                                                const int* __restrict__ mode) {
  gemm_body<1>(A, BT, C, *mode);
}

// ---------------- bias dots: c[b][h][j] = rwb_h . k_j ; e[h][p] = rrb_h . rel_p (padded) ----------------
__global__ __launch_bounds__(256) void cbias_kernel(const __hip_bfloat16* __restrict__ kp,
                                                    const void* __restrict__ rwb,
                                                    float* __restrict__ cb,
                                                    const int* __restrict__ mode) {
  const int md = *mode;
  const int idx = blockIdx.x * 256 + threadIdx.x;  // B*H*KL
  const int j = idx % KL_;
  const int h = (idx / KL_) % H_;
  const int b = idx / (KL_ * H_);
  const __hip_bfloat16* kr = kp + ((size_t)b * KL_ + j) * HID_ + h * D_;
  float s = 0.f;
#pragma unroll 8
  for (int d = 0; d < D_; d++) s += __bfloat162float(kr[d]) * ldin(rwb, h * D_ + d, md);
  cb[idx] = s;
}

__global__ __launch_bounds__(256) void ebias_kernel(const __hip_bfloat16* __restrict__ relp,
                                                    const void* __restrict__ rrb,
                                                    float* __restrict__ eb,
                                                    const int* __restrict__ mode) {
  const int md = *mode;
  const int idx = blockIdx.x * 256 + threadIdx.x;  // H*(KL+EPAD)
  const int p = idx % (KL_ + EPAD);
  const int h = idx / (KL_ + EPAD);
  const int pc = p < KL_ ? p : KL_ - 1;            // pad rows: finite junk (masked downstream)
  const __hip_bfloat16* rr = relp + (size_t)pc * HID_ + h * D_;
  float s = 0.f;
#pragma unroll 8
  for (int d = 0; d < D_; d++) s += __bfloat162float(rr[d]) * ldin(rrb, h * D_ + d, md);
  eb[idx] = s;
}

// ---------------- fused relative attention: LDS-staged operands, thread-owns-row softmax ----------------
// grid 1024 flat (XCD-remapped), block 256 (4 waves, each owns a 16-row q strip).
// K/rel/V^T staged to LDS once per block via global_load_lds (m97 idiom); MFMA A/B frags
// read from swizzled LDS; T-band/P round-trips in thread-private sTP rows (no barriers).
__global__ __launch_bounds__(256, 2) void attn_kernel(
    const __hip_bfloat16* __restrict__ qp, const __hip_bfloat16* __restrict__ kp,
    const __hip_bfloat16* __restrict__ vpt, const __hip_bfloat16* __restrict__ relp,
    const float* __restrict__ cb, const float* __restrict__ eb,
    const void* __restrict__ spanv, __hip_bfloat16* __restrict__ attn_out,
    const int* __restrict__ mode) {
  const int md = *mode;
  // XCD-locality remap: the 32 i0-blocks of one (b,h) share an XCD (bid%8 heuristic)
  const int bid = blockIdx.x;
  const int bh = (bid & 7) + 8 * (bid >> 8);
  const int i0 = ((bid >> 3) & 31) * RT_;
  const int b = bh >> 4, h = bh & 15;

  const int tid = threadIdx.x;
  const int lane = tid & 63;
  const int w = tid >> 6;
  const int quad = lane >> 4, l16 = lane & 15;
  const int di = w * 16 + l16;        // this thread's softmax row (block-local)
  const int iRow = i0 + di;
  const f32x4 fz = {0.f, 0.f, 0.f, 0.f};

  __shared__ __attribute__((aligned(16))) __hip_bfloat16 sk[128 * 64];    // 16 KB K tile (q staged here first)
  __shared__ __attribute__((aligned(16))) __hip_bfloat16 srel[192 * 64];  // 24 KB rel band
  __shared__ __attribute__((aligned(16))) __hip_bfloat16 svt[64 * 128];   // 16 KB V^T tile
  __shared__ __attribute__((aligned(16))) short sTP[64 * 152];            // 19 KB T-band/P, thread-private rows

  const __hip_bfloat16* kbase = kp + (size_t)b * KL_ * HID_ + h * D_;
  const __hip_bfloat16* vtb = vpt + ((size_t)(b * H_ + h)) * D_ * KL_;
  const float* cbb = cb + (size_t)(b * H_ + h) * KL_;
  const float* ebb = eb + (size_t)h * (KL_ + EPAD);
  const float sv = ldin(spanv, h, md);
  const int pb0 = Q_ - RT_ - i0;
  const int wof = (3 - w) * 16;       // this wave's T-band p-window offset
  const int ntiles = ((M_ + i0 + RT_ - 1) >> 7) + 1;

  // ---- stage q once via sk, read own-row B-fragments ----
  {
    const __hip_bfloat16* qb = qp + ((size_t)(b * Q_ + i0)) * HID_ + h * D_;
#pragma unroll
    for (int t = 0; t < 2; t++) {
      int c = (w * 2 + t) * 64 + lane;
      int row = c >> 3;
      int cid = (c & 7) ^ (row & 7);
      async_copy16(qb + (size_t)row * HID_ + cid * 8, (char*)sk + c * 16);
    }
  }
  __syncthreads();
  short8 qf[2];
#pragma unroll
  for (int ks = 0; ks < 2; ks++)
    qf[ks] = *(const short8*)((const char*)sk + di * 128 + (((ks * 4 + quad) ^ (di & 7)) * 16));

  float mrow = -3e38f, lrow = 0.f, lmrow = 0.f;
  f32x4 oacc[4];
#pragma unroll
  for (int dt = 0; dt < 4; dt++) oacc[dt] = fz;

  for (int kt = 0; kt < ntiles; kt++) {
    const int j0 = kt * WT_;
    const int pbase = pb0 + j0;

    __syncthreads();  // A: prior tile's LDS consumers done (also protects q-frag reads, tile 0)
    // ---- DMA staging: K (4), rel band (6), V^T (4) chunks per thread ----
#pragma unroll
    for (int t = 0; t < 4; t++) {
      int c = (w * 4 + t) * 64 + lane;
      int row = c >> 3;
      int cid = (c & 7) ^ (row & 7);
      async_copy16(kbase + (size_t)(j0 + row) * HID_ + cid * 8, (char*)sk + c * 16);
    }
#pragma unroll
    for (int t = 0; t < 6; t++) {
      int c = (w * 6 + t) * 64 + lane;
      int row = c >> 3;
      int cid = (c & 7) ^ (row & 7);
      int p = pbase + row; p = p < KL_ ? p : KL_ - 1;  // clamped rows feed only masked cols
      async_copy16(relp + (size_t)p * HID_ + h * D_ + cid * 8, (char*)srel + c * 16);
    }
#pragma unroll
    for (int t = 0; t < 4; t++) {
      int c = (w * 4 + t) * 64 + lane;
      int row = c >> 4;
      int cid = (c & 15) ^ (row & 15);
      async_copy16(vtb + (size_t)row * KL_ + j0 + cid * 8, (char*)svt + c * 16);
    }
    __syncthreads();  // B: DMA drained (compiler emits vmcnt(0) before barrier)

    // ---- S^T[j][i] = K . Q^T : A-frags from sk ----
    f32x4 S[8];
#pragma unroll
    for (int mt = 0; mt < 8; mt++) S[mt] = fz;
#pragma unroll
    for (int mt = 0; mt < 8; mt++) {
      int r = mt * 16 + l16;
#pragma unroll
      for (int ks = 0; ks < 2; ks++) {
        short8 af = *(const short8*)((const char*)sk + r * 128 + (((ks * 4 + quad) ^ (r & 7)) * 16));
        S[mt] = __builtin_amdgcn_mfma_f32_16x16x32_bf16(af, qf[ks], S[mt], 0, 0, 0);
      }
    }

    // ---- T band (wave's 144-col window), +e, unshifted store into own sTP row ----
#pragma unroll
    for (int mt = 0; mt < 9; mt++) {
      f32x4 T = fz;
      int r = wof + mt * 16 + l16;
#pragma unroll
      for (int ks = 0; ks < 2; ks++) {
        short8 af = *(const short8*)((const char*)srel + r * 128 + (((ks * 4 + quad) ^ (r & 7)) * 16));
        T = __builtin_amdgcn_mfma_f32_16x16x32_bf16(af, qf[ks], T, 0, 0, 0);
      }
      const int lo = mt * 16 + quad * 4;              // local band offset [0,144)
      f32x4 e4 = *(const f32x4*)(ebb + pbase + wof + lo);  // padded table: never OOB
      short4v pk;
#pragma unroll
      for (int rg = 0; rg < 4; rg++) pk[rg] = bfbits(T[rg] + e4[rg]);
      *(short4v*)(&sTP[di * 152 + lo]) = pk;
    }

    // ---- gather with per-row shift (own row: local base = 15 - l16) ----
#pragma unroll
    for (int mt = 0; mt < 8; mt++)
#pragma unroll
      for (int rg = 0; rg < 4; rg++) {
        int tcl = 15 - l16 + mt * 16 + quad * 4 + rg;
        S[mt][rg] += __bfloat162float(*(const __hip_bfloat16*)&sTP[di * 152 + tcl]);
      }

    // ---- logits, causal mask, online softmax ----
    float mnew = mrow;
#pragma unroll
    for (int mt = 0; mt < 8; mt++) {
      f32x4 cb4 = *(const f32x4*)(cbb + j0 + mt * 16 + quad * 4);
#pragma unroll
      for (int rg = 0; rg < 4; rg++) {
        int j = j0 + mt * 16 + quad * 4 + rg;
        float v = (S[mt][rg] + cb4[rg]) * (1.0f / 64.0f);
        if (j - iRow > M_) v = -1e30f;
        S[mt][rg] = v;
        mnew = fmaxf(mnew, v);
      }
    }
    mnew = fmaxf(mnew, __shfl_xor(mnew, 16));
    mnew = fmaxf(mnew, __shfl_xor(mnew, 32));
    const float alpha = __expf(mrow - mnew);
    mrow = mnew;
    lrow *= alpha; lmrow *= alpha;
    float aR[4];
#pragma unroll
    for (int rg = 0; rg < 4; rg++) aR[rg] = __shfl(alpha, quad * 4 + rg);
#pragma unroll
    for (int dt = 0; dt < 4; dt++)
#pragma unroll
      for (int rg = 0; rg < 4; rg++) oacc[dt][rg] *= aR[rg];

    // ---- P = exp(S-m)*span, packed b64 into own sTP row [0,128) ----
#pragma unroll
    for (int mt = 0; mt < 8; mt++) {
      short4v pk;
#pragma unroll
      for (int rg = 0; rg < 4; rg++) {
        int j = j0 + mt * 16 + quad * 4 + rg;
        float mk;
        if (j < M_) mk = 1.f;
        else {
          float t0 = (float)(j - M_) + sv * (float)Q_;
          mk = fminf(fmaxf(t0 * (1.0f / 33.0f), 0.f), 1.f);
        }
        float pv = __expf(S[mt][rg] - mrow);
        lrow += pv;
        float pm = pv * mk;
        lmrow += pm;
        pk[rg] = bfbits(pm);
      }
      *(short4v*)(&sTP[di * 152 + mt * 16 + quad * 4]) = pk;
    }

    // ---- PV: A = P (own rows), B = V^T rows from svt ----
#pragma unroll
    for (int ks = 0; ks < 4; ks++) {
      short8 af = *(const short8*)((const char*)sTP + di * 304 + ks * 64 + quad * 16);
#pragma unroll
      for (int dt = 0; dt < 4; dt++) {
        int r = dt * 16 + l16;
        short8 bfv = *(const short8*)((const char*)svt + r * 256 + (((ks * 4 + quad) ^ (r & 15)) * 16));
        oacc[dt] = __builtin_amdgcn_mfma_f32_16x16x32_bf16(af, bfv, oacc[dt], 0, 0, 0);
      }
    }
  }

  // ---- epilogue ----
  lrow += __shfl_xor(lrow, 16);  lrow += __shfl_xor(lrow, 32);
  lmrow += __shfl_xor(lmrow, 16); lmrow += __shfl_xor(lmrow, 32);
  float lr4[4], lm4[4];
#pragma unroll
  for (int rg = 0; rg < 4; rg++) {
    lr4[rg] = __shfl(lrow, quad * 4 + rg);
    lm4[rg] = __shfl(lmrow, quad * 4 + rg);
  }
#pragma unroll
  for (int dt = 0; dt < 4; dt++)
#pragma unroll
    for (int rg = 0; rg < 4; rg++) {
      int i = i0 + w * 16 + quad * 4 + rg;
      float denom = lm4[rg] + 1e-8f * lr4[rg];
      float ov = oacc[dt][rg] / denom;
      attn_out[((size_t)(b * Q_ + i)) * HID_ + h * D_ + dt * 16 + l16] = __float2bfloat16(ov);
    }
}

// ---------------- launcher ----------------
extern "C" void kernel_launch(void* const* d_in, const int* in_sizes, int n_in,
                              void* d_out, int out_size, void* d_ws, size_t ws_size,
                              hipStream_t stream) {
  const void* query  = d_in[0];
  const void* memory = d_in[1];
  const void* Wq = d_in[2];
  const void* Wk = d_in[3];
  const void* Wv = d_in[4];
  const void* Wo = d_in[5];
  const void* Wr = d_in[6];
  const void* gmem = d_in[7];
  const void* bmem = d_in[8];
  const void* gq = d_in[9];
  const void* bq = d_in[10];
  const void* rwb = d_in[11];
  const void* rrb = d_in[12];
  const void* spanv = d_in[13];

  char* ws = (char*)d_ws;
  size_t off = 0;
  auto alloc = [&](size_t bytes) -> char* {
    char* p = ws + off;
    off += (bytes + 255) & ~(size_t)255;
    return p;
  };
  int* flag = (int*)alloc(256);
  const size_t SZ_W = (size_t)HID_ * HID_ * 2;
  __hip_bfloat16* wqT = (__hip_bfloat16*)alloc(SZ_W);
  __hip_bfloat16* wkT = (__hip_bfloat16*)alloc(SZ_W);
  __hip_bfloat16* wvT = (__hip_bfloat16*)alloc(SZ_W);
  __hip_bfloat16* wrT = (__hip_bfloat16*)alloc(SZ_W);
  __hip_bfloat16* woT = (__hip_bfloat16*)alloc(SZ_W);
  __hip_bfloat16* kvln = (__hip_bfloat16*)alloc((size_t)B_ * KL_ * HID_ * 2);
  __hip_bfloat16* qln  = (__hip_bfloat16*)alloc((size_t)B_ * Q_ * HID_ * 2);
  __hip_bfloat16* pe   = (__hip_bfloat16*)alloc((size_t)KL_ * HID_ * 2);
  __hip_bfloat16* qpb  = (__hip_bfloat16*)alloc((size_t)B_ * Q_ * HID_ * 2);
  __hip_bfloat16* kpb  = (__hip_bfloat16*)alloc((size_t)B_ * KL_ * HID_ * 2);
  __hip_bfloat16* vpb  = (__hip_bfloat16*)alloc((size_t)B_ * KL_ * HID_ * 2);
  __hip_bfloat16* relp = (__hip_bfloat16*)alloc((size_t)KL_ * HID_ * 2);
  __hip_bfloat16* aout = (__hip_bfloat16*)alloc((size_t)B_ * Q_ * HID_ * 2);
  float* cbf = (float*)alloc((size_t)B_ * H_ * KL_ * 4);
  float* ebf = (float*)alloc((size_t)H_ * (KL_ + EPAD) * 4);
  __hip_bfloat16* vptb = kvln;  // alias: kvln dead after the k/v projection GEMMs

  dim3 tb(256);
  detect_kernel<<<dim3(1), tb, 0, stream>>>((const unsigned int*)query, flag);

  wt_kernel<<<dim3(16, 16), tb, 0, stream>>>(Wq, wqT, flag);
  wt_kernel<<<dim3(16, 16), tb, 0, stream>>>(Wk, wkT, flag);
  wt_kernel<<<dim3(16, 16), tb, 0, stream>>>(Wv, wvT, flag);
  wt_kernel<<<dim3(16, 16), tb, 0, stream>>>(Wr, wrT, flag);
  wt_kernel<<<dim3(16, 16), tb, 0, stream>>>(Wo, woT, flag);

  ln_kv_kernel<<<dim3(B_ * KL_), tb, 0, stream>>>(memory, query, gmem, bmem, kvln, flag);
  ln_q_kernel<<<dim3(B_ * Q_), tb, 0, stream>>>(query, gq, bq, qln, flag);
  posemb_kernel<<<dim3(KL_), tb, 0, stream>>>(pe);

  gemm_bt128<<<dim3(B_ * Q_ / 128, HID_ / 128), tb, 0, stream>>>(qln, wqT, qpb);
  gemm_bt128<<<dim3(B_ * KL_ / 128, HID_ / 128), tb, 0, stream>>>(kvln, wkT, kpb);
  gemm_bt128<<<dim3(B_ * KL_ / 128, HID_ / 128), tb, 0, stream>>>(kvln, wvT, vpb);
  gemm_bt128<<<dim3(KL_ / 128, HID_ / 128), tb, 0, stream>>>(pe, wrT, relp);

  vpt_kernel<<<dim3(KL_ / 64, B_ * H_), tb, 0, stream>>>(vpb, vptb);
  cbias_kernel<<<dim3(B_ * H_ * KL_ / 256), tb, 0, stream>>>(kpb, rwb, cbf, flag);
  ebias_kernel<<<dim3(H_ * (KL_ + EPAD) / 256), tb, 0, stream>>>(relp, rrb, ebf, flag);

  attn_kernel<<<dim3((Q_ / RT_) * H_ * B_), tb, 0, stream>>>(qpb, kpb, vptb, relp, cbf, ebf, spanv, aout, flag);

  gemm_out<<<dim3(B_ * Q_ / 128, HID_ / 128), tb, 0, stream>>>(aout, woT, d_out, flag);

  (void)in_sizes; (void)n_in; (void)out_size; (void)ws_size;
}

// Round 7
// 620.193 us; speedup vs baseline: 1.9867x; 1.0592x over previous
//
#include <hip/hip_runtime.h>
#include <hip/hip_bf16.h>
#include <math.h>

#define B_   2
#define Q_   2048
#define M_   2048
#define H_   16
#define D_   64
#define HID_ 1024
#define KL_  4096
#define RT_  64      // q rows per attention block
#define WT_  128     // k cols per attention tile
#define EPAD 256     // e-table tail padding (band reads past KL land here)
#define LSCL 0.022542110013890053f   // log2(e)/64 — logits kept in log2 units

typedef short short8 __attribute__((ext_vector_type(8)));
typedef short short4v __attribute__((ext_vector_type(4)));
typedef float f32x4 __attribute__((ext_vector_type(4)));

__device__ __forceinline__ void async_copy16(const void* g, void* l) {
  __builtin_amdgcn_global_load_lds((const __attribute__((address_space(1))) unsigned int*)g,
                                   (__attribute__((address_space(3))) unsigned int*)l,
                                   16, 0, 0);
}

// read input element i as float, md=1 -> fp32 buffer, md=0 -> bf16 buffer
__device__ __forceinline__ float ldin(const void* p, size_t i, int md) {
  return md ? ((const float*)p)[i] : __bfloat162float(((const __hip_bfloat16*)p)[i]);
}

__device__ __forceinline__ short bfbits(float v) {
  __hip_bfloat16 t = __float2bfloat16(v);
  return *(short*)&t;
}

// fast 2^x: lowers to v_exp_f32 (HW computes 2^x natively)
__device__ __forceinline__ float fexp2(float x) { return exp2f(x); }

// ---------------- dtype detector: writes 1 if inputs are fp32, else 0 ----------------
__global__ __launch_bounds__(256) void detect_kernel(const unsigned int* __restrict__ q,
                                                     int* __restrict__ flag) {
  __shared__ int cnt;
  if (threadIdx.x == 0) cnt = 0;
  __syncthreads();
  int ins = 0;
#pragma unroll
  for (int i = 0; i < 4; i++) {
    unsigned int u = q[threadIdx.x * 4 + i];
    int e0 = (int)((u >> 7) & 0xffu);
    int e1 = (int)((u >> 23) & 0xffu);
    if (e0 == 0xff || e0 < 102 || e0 > 140) ins++;
    if (e1 == 0xff || e1 < 102 || e1 > 140) ins++;
  }
  atomicAdd(&cnt, ins);
  __syncthreads();
  if (threadIdx.x == 0) *flag = (cnt > 512) ? 1 : 0;
}

// ---------------- fused weight transposes: wt[n][k] = src[k][n], 5 x 1024x1024 ----------------
__global__ __launch_bounds__(256) void wt5_kernel(
    const void* __restrict__ s0, const void* __restrict__ s1, const void* __restrict__ s2,
    const void* __restrict__ s3, const void* __restrict__ s4,
    __hip_bfloat16* __restrict__ d0, __hip_bfloat16* __restrict__ d1,
    __hip_bfloat16* __restrict__ d2, __hip_bfloat16* __restrict__ d3,
    __hip_bfloat16* __restrict__ d4, const int* __restrict__ mode) {
  const int md = *mode;
  const void* src; __hip_bfloat16* dst;
  switch (blockIdx.z) {
    case 0: src = s0; dst = d0; break;
    case 1: src = s1; dst = d1; break;
    case 2: src = s2; dst = d2; break;
    case 3: src = s3; dst = d3; break;
    default: src = s4; dst = d4; break;
  }
  const int r0 = blockIdx.x * 64, c0 = blockIdx.y * 64;
  __shared__ __hip_bfloat16 t[64][65];
  const int tid = threadIdx.x;
  const int col = tid & 63, r4 = tid >> 6;
#pragma unroll
  for (int i = 0; i < 16; i++)
    t[r4 + i * 4][col] = __float2bfloat16(ldin(src, (size_t)(r0 + r4 + i * 4) * HID_ + c0 + col, md));
  __syncthreads();
#pragma unroll
  for (int i = 0; i < 16; i++)
    dst[(size_t)(c0 + r4 + i * 4) * HID_ + r0 + col] = t[col][r4 + i * 4];
}

// ---------------- V transpose: vpt[b][h][d][j] = vp[b*K+j][h*64+d] ----------------
__global__ __launch_bounds__(256) void vpt_kernel(const __hip_bfloat16* __restrict__ vp,
                                                  __hip_bfloat16* __restrict__ vpt) {
  const int jt = blockIdx.x * 64;
  const int bh = blockIdx.y;
  const int b = bh / H_, h = bh % H_;
  __shared__ __hip_bfloat16 t[64][65];
  const int tid = threadIdx.x;
  const int col = tid & 63, r4 = tid >> 6;
#pragma unroll
  for (int i = 0; i < 16; i++) {
    int j = r4 + i * 4;
    t[j][col] = vp[((size_t)b * KL_ + jt + j) * HID_ + h * D_ + col];
  }
  __syncthreads();
#pragma unroll
  for (int i = 0; i < 16; i++) {
    int d = r4 + i * 4;
    vpt[(((size_t)b * H_ + h) * D_ + d) * KL_ + jt + col] = t[col][d];
  }
}

// ---------------- LayerNorm over concat(memory, query) rows ----------------
__global__ __launch_bounds__(256) void ln_kv_kernel(
    const void* __restrict__ mem, const void* __restrict__ qry,
    const void* __restrict__ gamma, const void* __restrict__ beta,
    __hip_bfloat16* __restrict__ out, const int* __restrict__ mode) {
  const int md = *mode;
  const int row = blockIdx.x;  // 0..B*KL-1
  const int b = row / KL_, j = row % KL_;
  const void* src;
  size_t base;
  if (j < M_) { src = mem; base = ((size_t)b * M_ + j) * HID_; }
  else        { src = qry; base = ((size_t)b * Q_ + (j - M_)) * HID_; }
  const int tid = threadIdx.x;
  float x[4];
  float s = 0.f, ss = 0.f;
#pragma unroll
  for (int i = 0; i < 4; i++) {
    x[i] = ldin(src, base + i * 256 + tid, md);
    s += x[i]; ss += x[i] * x[i];
  }
#pragma unroll
  for (int o = 32; o > 0; o >>= 1) { s += __shfl_down(s, o); ss += __shfl_down(ss, o); }
  __shared__ float red[8];
  if ((tid & 63) == 0) { red[(tid >> 6) * 2] = s; red[(tid >> 6) * 2 + 1] = ss; }
  __syncthreads();
  float ts = 0.f, tss = 0.f;
#pragma unroll
  for (int i = 0; i < 4; i++) { ts += red[i * 2]; tss += red[i * 2 + 1]; }
  const float mu = ts * (1.f / 1024.f);
  const float var = tss * (1.f / 1024.f) - mu * mu;
  const float rs = rsqrtf(var + 1e-3f);
  __hip_bfloat16* dst = out + (size_t)row * HID_;
#pragma unroll
  for (int i = 0; i < 4; i++) {
    int c = i * 256 + tid;
    dst[c] = __float2bfloat16((x[i] - mu) * rs * ldin(gamma, c, md) + ldin(beta, c, md));
  }
}

__global__ __launch_bounds__(256) void ln_q_kernel(
    const void* __restrict__ qry,
    const void* __restrict__ gamma, const void* __restrict__ beta,
    __hip_bfloat16* __restrict__ out, const int* __restrict__ mode) {
  const int md = *mode;
  const int row = blockIdx.x;  // 0..B*Q-1
  const size_t base = (size_t)row * HID_;
  const int tid = threadIdx.x;
  float x[4];
  float s = 0.f, ss = 0.f;
#pragma unroll
  for (int i = 0; i < 4; i++) {
    x[i] = ldin(qry, base + i * 256 + tid, md);
    s += x[i]; ss += x[i] * x[i];
  }
#pragma unroll
  for (int o = 32; o > 0; o >>= 1) { s += __shfl_down(s, o); ss += __shfl_down(ss, o); }
  __shared__ float red[8];
  if ((tid & 63) == 0) { red[(tid >> 6) * 2] = s; red[(tid >> 6) * 2 + 1] = ss; }
  __syncthreads();
  float ts = 0.f, tss = 0.f;
#pragma unroll
  for (int i = 0; i < 4; i++) { ts += red[i * 2]; tss += red[i * 2 + 1]; }
  const float mu = ts * (1.f / 1024.f);
  const float var = tss * (1.f / 1024.f) - mu * mu;
  const float rs = rsqrtf(var + 1e-3f);
  __hip_bfloat16* dst = out + (size_t)row * HID_;
#pragma unroll
  for (int i = 0; i < 4; i++) {
    int c = i * 256 + tid;
    dst[c] = __float2bfloat16((x[i] - mu) * rs * ldin(gamma, c, md) + ldin(beta, c, md));
  }
}

// ---------------- sinusoidal position embedding, positions K-1..0 ----------------
__global__ __launch_bounds__(256) void posemb_kernel(__hip_bfloat16* __restrict__ pe) {
  const int p = blockIdx.x;
  const float pos = (float)(KL_ - 1 - p);
  const int tid = threadIdx.x;
#pragma unroll
  for (int i = 0; i < 4; i++) {
    int c = tid * 4 + i;
    int f = (c < 512) ? c : c - 512;
    float invf = fexp2(-(float)f * (13.287712379549449f / 512.0f));
    float a = pos * invf;
    float v = (c < 512) ? __sinf(a) : __cosf(a);
    pe[(size_t)p * HID_ + c] = __float2bfloat16(v);
  }
}

// ---------------- GEMM core: C = A @ BT^T (both bf16, K=1024), 128x128 tile ----------------
template <int WRITE_MODE_SWITCH>
__device__ __forceinline__ void gemm_body(const __hip_bfloat16* __restrict__ A,
                                          const __hip_bfloat16* __restrict__ BT,
                                          void* __restrict__ C, int md, float scl) {
  __shared__ __attribute__((aligned(16))) __hip_bfloat16 sA[128 * 32];
  __shared__ __attribute__((aligned(16))) __hip_bfloat16 sB[128 * 32];
  const int tid = threadIdx.x;
  const int lane = tid & 63;
  const int w = tid >> 6;
  const int quad = lane >> 4, l16 = lane & 15;
  const int m0 = blockIdx.x * 128;
  const int n0 = blockIdx.y * 128;
  const int wm = (w >> 1) * 64, wn = (w & 1) * 64;
  const f32x4 fz = {0.f, 0.f, 0.f, 0.f};

  f32x4 acc[4][4];
#pragma unroll
  for (int i = 0; i < 4; i++)
#pragma unroll
    for (int j = 0; j < 4; j++) acc[i][j] = fz;

  for (int kk = 0; kk < HID_ / 32; kk++) {
    const int k0 = kk * 32;
    __syncthreads();
#pragma unroll
    for (int t = 0; t < 2; t++) {
      int c = (w * 2 + t) * 64 + lane;
      int row = c >> 2;
      int cid = (c & 3) ^ (row & 3);
      async_copy16(A + (size_t)(m0 + row) * HID_ + k0 + cid * 8, (char*)sA + c * 16);
      async_copy16(BT + (size_t)(n0 + row) * HID_ + k0 + cid * 8, (char*)sB + c * 16);
    }
    __syncthreads();
    short8 af[4], bf[4];
#pragma unroll
    for (int mt = 0; mt < 4; mt++) {
      int r = wm + mt * 16 + l16;
      af[mt] = *(const short8*)((const char*)sA + r * 64 + ((quad ^ (r & 3)) * 16));
    }
#pragma unroll
    for (int nt = 0; nt < 4; nt++) {
      int r = wn + nt * 16 + l16;
      bf[nt] = *(const short8*)((const char*)sB + r * 64 + ((quad ^ (r & 3)) * 16));
    }
#pragma unroll
    for (int mt = 0; mt < 4; mt++)
#pragma unroll
      for (int nt = 0; nt < 4; nt++)
        acc[mt][nt] = __builtin_amdgcn_mfma_f32_16x16x32_bf16(af[mt], bf[nt], acc[mt][nt], 0, 0, 0);
  }
#pragma unroll
  for (int mt = 0; mt < 4; mt++)
#pragma unroll
    for (int nt = 0; nt < 4; nt++)
#pragma unroll
      for (int rg = 0; rg < 4; rg++) {
        int r = m0 + wm + mt * 16 + quad * 4 + rg;
        int cc = n0 + wn + nt * 16 + l16;
        size_t idx = (size_t)r * HID_ + cc;
        if (WRITE_MODE_SWITCH && md) ((float*)C)[idx] = acc[mt][nt][rg];
        else ((__hip_bfloat16*)C)[idx] = __float2bfloat16(acc[mt][nt][rg] * scl);
      }
}

__global__ __launch_bounds__(256) void gemm_bt128(const __hip_bfloat16* __restrict__ A,
                                                  const __hip_bfloat16* __restrict__ BT,
                                                  __hip_bfloat16* __restrict__ C, float scl) {
  gemm_body<0>(A, BT, (void*)C, 0, scl);
}

__global__ __launch_bounds__(256) void gemm_out(const __hip_bfloat16* __restrict__ A,
                                                const __hip_bfloat16* __restrict__ BT,
                                                void* __restrict__ C,
                                                const int* __restrict__ mode) {
  gemm_body<1>(A, BT, C, *mode, 1.0f);
}

// ---------------- bias dots (pre-scaled by log2e/64) ----------------
__global__ __launch_bounds__(256) void cbias_kernel(const __hip_bfloat16* __restrict__ kp,
                                                    const void* __restrict__ rwb,
                                                    float* __restrict__ cb,
                                                    const int* __restrict__ mode) {
  const int md = *mode;
  const int idx = blockIdx.x * 256 + threadIdx.x;  // B*H*KL
  const int j = idx % KL_;
  const int h = (idx / KL_) % H_;
  const int b = idx / (KL_ * H_);
  const __hip_bfloat16* kr = kp + ((size_t)b * KL_ + j) * HID_ + h * D_;
  float s = 0.f;
#pragma unroll
  for (int t = 0; t < 8; t++) {
    short8 v = *(const short8*)(kr + t * 8);
#pragma unroll
    for (int u = 0; u < 8; u++) {
      short sb = v[u];
      s += __bfloat162float(*(__hip_bfloat16*)&sb) * ldin(rwb, h * D_ + t * 8 + u, md);
    }
  }
  cb[idx] = s * LSCL;
}

__global__ __launch_bounds__(256) void ebias_kernel(const __hip_bfloat16* __restrict__ relp,
                                                    const void* __restrict__ rrb,
                                                    float* __restrict__ eb,
                                                    const int* __restrict__ mode) {
  const int md = *mode;
  const int idx = blockIdx.x * 256 + threadIdx.x;  // H*(KL+EPAD)
  const int p = idx % (KL_ + EPAD);
  const int h = idx / (KL_ + EPAD);
  const int pc = p < KL_ ? p : KL_ - 1;            // pad rows: finite junk (masked downstream)
  const __hip_bfloat16* rr = relp + (size_t)pc * HID_ + h * D_;
  float s = 0.f;
#pragma unroll
  for (int t = 0; t < 8; t++) {
    short8 v = *(const short8*)(rr + t * 8);
#pragma unroll
    for (int u = 0; u < 8; u++) {
      short sb = v[u];
      s += __bfloat162float(*(__hip_bfloat16*)&sb) * ldin(rrb, h * D_ + t * 8 + u, md);
    }
  }
  eb[idx] = s * LSCL;
}

// ---------------- fused relative attention ----------------
// grid 1024 flat (XCD-remapped), block 256 (4 waves). Logits in log2 units (q/cb/eb
// pre-scaled by log2e/64). K+rel staged at barrier B; V DMA issued after B, drained at
// barrier C before PV (covered by S/T/softmax). sTP rows: stride 312B + 8B odd-row shift
// (16B-aligned rows, addr period 16 -> 4-way max bank aliasing).
__global__ __launch_bounds__(256, 2) void attn_kernel(
    const __hip_bfloat16* __restrict__ qp, const __hip_bfloat16* __restrict__ kp,
    const __hip_bfloat16* __restrict__ vpt, const __hip_bfloat16* __restrict__ relp,
    const float* __restrict__ cb, const float* __restrict__ eb,
    const void* __restrict__ spanv, __hip_bfloat16* __restrict__ attn_out,
    const int* __restrict__ mode) {
  const int md = *mode;
  const int bid = blockIdx.x;
  const int bh = (bid & 7) + 8 * (bid >> 8);
  const int i0 = ((bid >> 3) & 31) * RT_;
  const int b = bh >> 4, h = bh & 15;

  const int tid = threadIdx.x;
  const int lane = tid & 63;
  const int w = tid >> 6;
  const int quad = lane >> 4, l16 = lane & 15;
  const int di = w * 16 + l16;        // this thread's softmax row (block-local)
  const int iRow = i0 + di;
  const f32x4 fz = {0.f, 0.f, 0.f, 0.f};

  __shared__ __attribute__((aligned(16))) __hip_bfloat16 sk[128 * 64];    // 16 KB K tile (q staged here first)
  __shared__ __attribute__((aligned(16))) __hip_bfloat16 srel[192 * 64];  // 24 KB rel band
  __shared__ __attribute__((aligned(16))) __hip_bfloat16 svt[64 * 128];   // 16 KB V^T tile
  __shared__ __attribute__((aligned(16))) short sTP[64 * 156];            // 19.5 KB T-band/P rows

  const int rb = di * 312 + ((di & 1) << 3);  // 16B-aligned private row base (bytes)

  const __hip_bfloat16* kbase = kp + (size_t)b * KL_ * HID_ + h * D_;
  const __hip_bfloat16* vtb = vpt + ((size_t)(b * H_ + h)) * D_ * KL_;
  const float* cbb = cb + (size_t)(b * H_ + h) * KL_;
  const float* ebb = eb + (size_t)h * (KL_ + EPAD);
  const float sv = ldin(spanv, h, md);
  const float svQ = sv * (float)Q_;
  const int pb0 = Q_ - RT_ - i0;
  const int wof = (3 - w) * 16;       // this wave's T-band p-window offset
  const int ntiles = ((M_ + i0 + RT_ - 1) >> 7) + 1;

  // ---- stage q once via sk, read own-row B-fragments ----
  {
    const __hip_bfloat16* qb = qp + ((size_t)(b * Q_ + i0)) * HID_ + h * D_;
#pragma unroll
    for (int t = 0; t < 2; t++) {
      int c = (w * 2 + t) * 64 + lane;
      int row = c >> 3;
      int cid = (c & 7) ^ (row & 7);
      async_copy16(qb + (size_t)row * HID_ + cid * 8, (char*)sk + c * 16);
    }
  }
  __syncthreads();
  short8 qf[2];
#pragma unroll
  for (int ks = 0; ks < 2; ks++)
    qf[ks] = *(const short8*)((const char*)sk + di * 128 + (((ks * 4 + quad) ^ (di & 7)) * 16));

  float mrow = -3e38f, lrow = 0.f, dfrow = 0.f;
  f32x4 oacc[4];
#pragma unroll
  for (int dt = 0; dt < 4; dt++) oacc[dt] = fz;

  for (int kt = 0; kt < ntiles; kt++) {
    const int j0 = kt * WT_;
    const int pbase = pb0 + j0;

    __syncthreads();  // A: prior tile's sk/srel MFMA reads done (and q-frag reads, tile 0)
    // ---- DMA staging: K (4), rel band (6) ----
#pragma unroll
    for (int t = 0; t < 4; t++) {
      int c = (w * 4 + t) * 64 + lane;
      int row = c >> 3;
      int cid = (c & 7) ^ (row & 7);
      async_copy16(kbase + (size_t)(j0 + row) * HID_ + cid * 8, (char*)sk + c * 16);
    }
#pragma unroll
    for (int t = 0; t < 6; t++) {
      int c = (w * 6 + t) * 64 + lane;
      int row = c >> 3;
      int cid = (c & 7) ^ (row & 7);
      int p = pbase + row; p = p < KL_ ? p : KL_ - 1;  // clamped rows feed only masked cols
      async_copy16(relp + (size_t)p * HID_ + h * D_ + cid * 8, (char*)srel + c * 16);
    }
    __syncthreads();  // B: K+rel drained (40 KB, not 56)

    // ---- V^T DMA issued now, drained at barrier C (covered by S/T/softmax) ----
    // svt's last reads (prev PV) happened before barrier A.
#pragma unroll
    for (int t = 0; t < 4; t++) {
      int c = (w * 4 + t) * 64 + lane;
      int row = c >> 4;
      int cid = (c & 15) ^ (row & 15);
      async_copy16(vtb + (size_t)row * KL_ + j0 + cid * 8, (char*)svt + c * 16);
    }

    // ---- S^T[j][i] = K . Q^T ----
    f32x4 S[8];
#pragma unroll
    for (int mt = 0; mt < 8; mt++) S[mt] = fz;
#pragma unroll
    for (int mt = 0; mt < 8; mt++) {
      int r = mt * 16 + l16;
#pragma unroll
      for (int ks = 0; ks < 2; ks++) {
        short8 af = *(const short8*)((const char*)sk + r * 128 + (((ks * 4 + quad) ^ (r & 7)) * 16));
        S[mt] = __builtin_amdgcn_mfma_f32_16x16x32_bf16(af, qf[ks], S[mt], 0, 0, 0);
      }
    }

    // ---- T band (wave's 144-col window), +e, store into own sTP row ----
#pragma unroll
    for (int mt = 0; mt < 9; mt++) {
      f32x4 T = fz;
      int r = wof + mt * 16 + l16;
#pragma unroll
      for (int ks = 0; ks < 2; ks++) {
        short8 af = *(const short8*)((const char*)srel + r * 128 + (((ks * 4 + quad) ^ (r & 7)) * 16));
        T = __builtin_amdgcn_mfma_f32_16x16x32_bf16(af, qf[ks], T, 0, 0, 0);
      }
      const int lo = mt * 16 + quad * 4;              // local band offset [0,144)
      f32x4 e4 = *(const f32x4*)(ebb + pbase + wof + lo);
      short4v pk;
#pragma unroll
      for (int rg = 0; rg < 4; rg++) pk[rg] = bfbits(T[rg] + e4[rg]);
      *(short4v*)((char*)sTP + rb + lo * 2) = pk;
    }

    // ---- gather with per-row shift (own row, in-order DS) ----
#pragma unroll
    for (int mt = 0; mt < 8; mt++)
#pragma unroll
      for (int rg = 0; rg < 4; rg++) {
        int tcl = 15 - l16 + mt * 16 + quad * 4 + rg;
        S[mt][rg] += __bfloat162float(*(const __hip_bfloat16*)((const char*)sTP + rb + tcl * 2));
      }

    // ---- logits (log2 units), causal mask only on tiles that can need it ----
    const bool causalT = (j0 + WT_ - 1 - i0) > M_;
    float mnew = mrow;
#pragma unroll
    for (int mt = 0; mt < 8; mt++) {
      f32x4 cb4 = *(const f32x4*)(cbb + j0 + mt * 16 + quad * 4);
#pragma unroll
      for (int rg = 0; rg < 4; rg++) {
        float v = S[mt][rg] + cb4[rg];
        if (causalT) {
          int j = j0 + mt * 16 + quad * 4 + rg;
          if (j - iRow > M_) v = -1e30f;
        }
        S[mt][rg] = v;
        mnew = fmaxf(mnew, v);
      }
    }
    mnew = fmaxf(mnew, __shfl_xor(mnew, 16));
    mnew = fmaxf(mnew, __shfl_xor(mnew, 32));
    const float alpha = fexp2(mrow - mnew);
    mrow = mnew;
    lrow *= alpha; dfrow *= alpha;
    float aR[4];
#pragma unroll
    for (int rg = 0; rg < 4; rg++) aR[rg] = __shfl(alpha, quad * 4 + rg);
#pragma unroll
    for (int dt = 0; dt < 4; dt++)
#pragma unroll
      for (int rg = 0; rg < 4; rg++) oacc[dt][rg] *= aR[rg];

    // ---- P = exp2(S-m); span deficit only on tiles overlapping the ramp ----
    const bool maskT = (j0 + WT_ > M_) && ((float)j0 < (float)M_ + 33.f - svQ);
#pragma unroll
    for (int mt = 0; mt < 8; mt++) {
      short4v pk;
#pragma unroll
      for (int rg = 0; rg < 4; rg++) {
        float pv = fexp2(S[mt][rg] - mrow);
        lrow += pv;
        float pm = pv;
        if (maskT) {
          int j = j0 + mt * 16 + quad * 4 + rg;
          if (j >= M_) {
            float t0 = (float)(j - M_) + svQ;
            float mk = fminf(fmaxf(t0 * (1.0f / 33.0f), 0.f), 1.f);
            pm = pv * mk;
            dfrow += pv - pm;
          }
        }
        pk[rg] = bfbits(pm);
      }
      *(short4v*)((char*)sTP + rb + (mt * 16 + quad * 4) * 2) = pk;
    }

    __syncthreads();  // C: V^T DMA visible block-wide (long since landed)

    // ---- PV: A = P (own rows, b128 from 16B-aligned sTP), B = V^T rows from svt ----
#pragma unroll
    for (int ks = 0; ks < 4; ks++) {
      short8 af = *(const short8*)((const char*)sTP + rb + ks * 64 + quad * 16);
#pragma unroll
      for (int dt = 0; dt < 4; dt++) {
        int r = dt * 16 + l16;
        short8 bfv = *(const short8*)((const char*)svt + r * 256 + (((ks * 4 + quad) ^ (r & 15)) * 16));
        oacc[dt] = __builtin_amdgcn_mfma_f32_16x16x32_bf16(af, bfv, oacc[dt], 0, 0, 0);
      }
    }
  }

  // ---- epilogue: lm = lr - deficit ----
  lrow += __shfl_xor(lrow, 16);  lrow += __shfl_xor(lrow, 32);
  dfrow += __shfl_xor(dfrow, 16); dfrow += __shfl_xor(dfrow, 32);
  float lr4[4], df4[4];
#pragma unroll
  for (int rg = 0; rg < 4; rg++) {
    lr4[rg] = __shfl(lrow, quad * 4 + rg);
    df4[rg] = __shfl(dfrow, quad * 4 + rg);
  }
#pragma unroll
  for (int dt = 0; dt < 4; dt++)
#pragma unroll
    for (int rg = 0; rg < 4; rg++) {
      int i = i0 + w * 16 + quad * 4 + rg;
      float denom = (lr4[rg] - df4[rg]) + 1e-8f * lr4[rg];
      float ov = oacc[dt][rg] / denom;
      attn_out[((size_t)(b * Q_ + i)) * HID_ + h * D_ + dt * 16 + l16] = __float2bfloat16(ov);
    }
}

// ---------------- launcher ----------------
extern "C" void kernel_launch(void* const* d_in, const int* in_sizes, int n_in,
                              void* d_out, int out_size, void* d_ws, size_t ws_size,
                              hipStream_t stream) {
  const void* query  = d_in[0];
  const void* memory = d_in[1];
  const void* Wq = d_in[2];
  const void* Wk = d_in[3];
  const void* Wv = d_in[4];
  const void* Wo = d_in[5];
  const void* Wr = d_in[6];
  const void* gmem = d_in[7];
  const void* bmem = d_in[8];
  const void* gq = d_in[9];
  const void* bq = d_in[10];
  const void* rwb = d_in[11];
  const void* rrb = d_in[12];
  const void* spanv = d_in[13];

  char* ws = (char*)d_ws;
  size_t off = 0;
  auto alloc = [&](size_t bytes) -> char* {
    char* p = ws + off;
    off += (bytes + 255) & ~(size_t)255;
    return p;
  };
  int* flag = (int*)alloc(256);
  const size_t SZ_W = (size_t)HID_ * HID_ * 2;
  __hip_bfloat16* wqT = (__hip_bfloat16*)alloc(SZ_W);
  __hip_bfloat16* wkT = (__hip_bfloat16*)alloc(SZ_W);
  __hip_bfloat16* wvT = (__hip_bfloat16*)alloc(SZ_W);
  __hip_bfloat16* wrT = (__hip_bfloat16*)alloc(SZ_W);
  __hip_bfloat16* woT = (__hip_bfloat16*)alloc(SZ_W);
  __hip_bfloat16* kvln = (__hip_bfloat16*)alloc((size_t)B_ * KL_ * HID_ * 2);
  __hip_bfloat16* qln  = (__hip_bfloat16*)alloc((size_t)B_ * Q_ * HID_ * 2);
  __hip_bfloat16* pe   = (__hip_bfloat16*)alloc((size_t)KL_ * HID_ * 2);
  __hip_bfloat16* qpb  = (__hip_bfloat16*)alloc((size_t)B_ * Q_ * HID_ * 2);
  __hip_bfloat16* kpb  = (__hip_bfloat16*)alloc((size_t)B_ * KL_ * HID_ * 2);
  __hip_bfloat16* vpb  = (__hip_bfloat16*)alloc((size_t)B_ * KL_ * HID_ * 2);
  __hip_bfloat16* relp = (__hip_bfloat16*)alloc((size_t)KL_ * HID_ * 2);
  __hip_bfloat16* aout = (__hip_bfloat16*)alloc((size_t)B_ * Q_ * HID_ * 2);
  float* cbf = (float*)alloc((size_t)B_ * H_ * KL_ * 4);
  float* ebf = (float*)alloc((size_t)H_ * (KL_ + EPAD) * 4);
  __hip_bfloat16* vptb = kvln;  // alias: kvln dead after the k/v projection GEMMs

  dim3 tb(256);
  detect_kernel<<<dim3(1), tb, 0, stream>>>((const unsigned int*)query, flag);

  wt5_kernel<<<dim3(16, 16, 5), tb, 0, stream>>>(Wq, Wk, Wv, Wr, Wo,
                                                 wqT, wkT, wvT, wrT, woT, flag);

  ln_kv_kernel<<<dim3(B_ * KL_), tb, 0, stream>>>(memory, query, gmem, bmem, kvln, flag);
  ln_q_kernel<<<dim3(B_ * Q_), tb, 0, stream>>>(query, gq, bq, qln, flag);
  posemb_kernel<<<dim3(KL_), tb, 0, stream>>>(pe);

  gemm_bt128<<<dim3(B_ * Q_ / 128, HID_ / 128), tb, 0, stream>>>(qln, wqT, qpb, LSCL);
  gemm_bt128<<<dim3(B_ * KL_ / 128, HID_ / 128), tb, 0, stream>>>(kvln, wkT, kpb, 1.0f);
  gemm_bt128<<<dim3(B_ * KL_ / 128, HID_ / 128), tb, 0, stream>>>(kvln, wvT, vpb, 1.0f);
  gemm_bt128<<<dim3(KL_ / 128, HID_ / 128), tb, 0, stream>>>(pe, wrT, relp, 1.0f);

  vpt_kernel<<<dim3(KL_ / 64, B_ * H_), tb, 0, stream>>>(vpb, vptb);
  cbias_kernel<<<dim3(B_ * H_ * KL_ / 256), tb, 0, stream>>>(kpb, rwb, cbf, flag);
  ebias_kernel<<<dim3(H_ * (KL_ + EPAD) / 256), tb, 0, stream>>>(relp, rrb, ebf, flag);

  attn_kernel<<<dim3((Q_ / RT_) * H_ * B_), tb, 0, stream>>>(qpb, kpb, vptb, relp, cbf, ebf, spanv, aout, flag);

  gemm_out<<<dim3(B_ * Q_ / 128, HID_ / 128), tb, 0, stream>>>(aout, woT, d_out, flag);

  (void)in_sizes; (void)n_in; (void)out_size; (void)ws_size;
}